// Round 17
// baseline (422.932 us; speedup 1.0000x reference)
//
#include <hip/hip_runtime.h>
#include <hip/hip_bf16.h>
#include <math.h>

// Problem constants
#define SDIM 512
#define BATCH 64
#define LSEQ 512
#define NHEAD 4
#define HDIM 128
#define NAA 20
#define NROWS (BATCH * LSEQ)   // 32768
#define LDQKV 1536

typedef __attribute__((ext_vector_type(8))) short short8;
typedef __attribute__((ext_vector_type(4))) float f32x4;

__device__ __forceinline__ unsigned short f2bf(float f) {
    unsigned int x = __float_as_uint(f);
    unsigned int r = (x + 0x7fffu + ((x >> 16) & 1u)) >> 16;  // RNE
    return (unsigned short)r;
}
__device__ __forceinline__ float bf2f(unsigned short u) {
    return __uint_as_float((unsigned int)u << 16);
}

__device__ __forceinline__ void load16_lds(const void* g, void* lds) {
    __builtin_amdgcn_global_load_lds(
        (const __attribute__((address_space(1))) unsigned int*)g,
        (__attribute__((address_space(3))) unsigned int*)lds, 16, 0, 0);
}

// ---------------------------------------------------------------------------
// Weight transpose + bf16 convert: W[K][N] fp32 -> Wt[N][K] bf16
// ---------------------------------------------------------------------------
__global__ __launch_bounds__(256) void wtrans(
    const float* __restrict__ W, unsigned short* __restrict__ Wt, int K, int N)
{
    __shared__ float tile[32][33];
    const int t = threadIdx.x, tx = t & 31, ty = t >> 5;
    const int n0 = blockIdx.x * 32, k0 = blockIdx.y * 32;
    #pragma unroll
    for (int p = 0; p < 4; p++)
        tile[ty + p * 8][tx] = W[(size_t)(k0 + ty + p * 8) * N + n0 + tx];
    __syncthreads();
    #pragma unroll
    for (int p = 0; p < 4; p++)
        Wt[(size_t)(n0 + ty + p * 8) * K + k0 + tx] = f2bf(tile[tx][ty + p * 8]);
}

// wp [512][20] fp32 -> wpT [32][512] bf16, rows 20..31 zero
__global__ __launch_bounds__(256) void wptrans(
    const float* __restrict__ wp, unsigned short* __restrict__ wpT)
{
    const int g = blockIdx.x * 256 + threadIdx.x;
    const int k = g & 511, j = g >> 9;
    float v = (j < NAA) ? wp[(size_t)k * NAA + j] : 0.0f;
    wpT[(size_t)j * 512 + k] = f2bf(v);
}

// pack bq|bk|bv into one 1536 vector
__global__ void bpack(const float* __restrict__ bq, const float* __restrict__ bk,
                      const float* __restrict__ bv, float* __restrict__ bqkv)
{
    int t = threadIdx.x;  // 512
    bqkv[t] = bq[t]; bqkv[512 + t] = bk[t]; bqkv[1024 + t] = bv[t];
}

// ---------------------------------------------------------------------------
// LayerNorm: one WAVE per row, no LDS/barriers. INMODE 0=fp32 in, 1=bf16 in.
// ---------------------------------------------------------------------------
template<int INMODE, bool AFFINE>
__global__ __launch_bounds__(256) void ln_kernel(
    const void* __restrict__ inp, unsigned short* __restrict__ out,
    const float* __restrict__ gamma, const float* __restrict__ beta)
{
    const int w = threadIdx.x >> 6, l = threadIdx.x & 63;
    const int r = blockIdx.x * 4 + w;

    float x[8];
    if (INMODE == 0) {
        const float* row = (const float*)inp + (size_t)r * SDIM;
        float4 a = *(const float4*)(row + l * 4);
        float4 b = *(const float4*)(row + 256 + l * 4);
        x[0] = a.x; x[1] = a.y; x[2] = a.z; x[3] = a.w;
        x[4] = b.x; x[5] = b.y; x[6] = b.z; x[7] = b.w;
    } else {
        const unsigned short* row = (const unsigned short*)inp + (size_t)r * SDIM;
        uint2 a = *(const uint2*)(row + l * 4);
        uint2 b = *(const uint2*)(row + 256 + l * 4);
        x[0] = bf2f((unsigned short)(a.x & 0xffff)); x[1] = bf2f((unsigned short)(a.x >> 16));
        x[2] = bf2f((unsigned short)(a.y & 0xffff)); x[3] = bf2f((unsigned short)(a.y >> 16));
        x[4] = bf2f((unsigned short)(b.x & 0xffff)); x[5] = bf2f((unsigned short)(b.x >> 16));
        x[6] = bf2f((unsigned short)(b.y & 0xffff)); x[7] = bf2f((unsigned short)(b.y >> 16));
    }

    float sum = 0.f, sq = 0.f;
    #pragma unroll
    for (int i = 0; i < 8; i++) { sum += x[i]; sq += x[i] * x[i]; }
    #pragma unroll
    for (int o = 1; o < 64; o <<= 1) {
        sum += __shfl_xor(sum, o);
        sq  += __shfl_xor(sq, o);
    }
    const float mean = sum * (1.0f / SDIM);
    const float var  = sq * (1.0f / SDIM) - mean * mean;
    const float inv  = rsqrtf(var + 1e-5f);

    float y[8];
    if (AFFINE) {
        float4 g0 = *(const float4*)(gamma + l * 4);
        float4 g1 = *(const float4*)(gamma + 256 + l * 4);
        float4 b0 = *(const float4*)(beta + l * 4);
        float4 b1 = *(const float4*)(beta + 256 + l * 4);
        y[0] = (x[0]-mean)*inv*g0.x + b0.x; y[1] = (x[1]-mean)*inv*g0.y + b0.y;
        y[2] = (x[2]-mean)*inv*g0.z + b0.z; y[3] = (x[3]-mean)*inv*g0.w + b0.w;
        y[4] = (x[4]-mean)*inv*g1.x + b1.x; y[5] = (x[5]-mean)*inv*g1.y + b1.y;
        y[6] = (x[6]-mean)*inv*g1.z + b1.z; y[7] = (x[7]-mean)*inv*g1.w + b1.w;
    } else {
        #pragma unroll
        for (int i = 0; i < 8; i++) y[i] = (x[i] - mean) * inv;
    }

    unsigned short* orow = out + (size_t)r * SDIM;
    uint2 p0, p1;
    p0.x = (unsigned)f2bf(y[0]) | ((unsigned)f2bf(y[1]) << 16);
    p0.y = (unsigned)f2bf(y[2]) | ((unsigned)f2bf(y[3]) << 16);
    p1.x = (unsigned)f2bf(y[4]) | ((unsigned)f2bf(y[5]) << 16);
    p1.y = (unsigned)f2bf(y[6]) | ((unsigned)f2bf(y[7]) << 16);
    *(uint2*)(orow + l * 4)       = p0;
    *(uint2*)(orow + 256 + l * 4) = p1;
}

// ---------------------------------------------------------------------------
// Profile kernel: logits = s_ln(bf16) @ wpT^T + bp, softmax+entropy epilogue.
// ---------------------------------------------------------------------------
__global__ __launch_bounds__(256) void profile_kernel(
    const unsigned short* __restrict__ A,
    const unsigned short* __restrict__ wpT,
    const float* __restrict__ bp,
    float* __restrict__ probs,
    float* __restrict__ pe)
{
    __shared__ __align__(16) unsigned short As[128 * 64];

    const int t = threadIdx.x;
    const int w = t >> 6, l = t & 63;
    const int lr = l & 15, lg = l >> 4;
    const int m0 = blockIdx.x * 128;

    f32x4 sacc[2][2];
    #pragma unroll
    for (int m = 0; m < 2; m++)
        #pragma unroll
        for (int n = 0; n < 2; n++)
            sacc[m][n] = (f32x4){0.f, 0.f, 0.f, 0.f};

    const int srow  = l >> 3;
    const int swz16 = ((l & 7) ^ srow) << 4;
    const char* pA[4];
    unsigned ldsoff[4];
    #pragma unroll
    for (int i = 0; i < 4; i++) {
        const int row = (w * 4 + i) * 8 + srow;
        pA[i] = (const char*)A + (size_t)(m0 + row) * 1024 + swz16;
        ldsoff[i] = (unsigned)(w * 4 + i) * 1024;
    }

    const int rsw   = (lr & 7) << 4;
    const int foff0 = (lg * 16) ^ rsw;
    const int foff1 = (64 + lg * 16) ^ rsw;
    int arow[2];
    #pragma unroll
    for (int m = 0; m < 2; m++) arow[m] = (w * 32 + m * 16 + lr) * 128;

    for (int k0 = 0; k0 < 512; k0 += 64) {
        const size_t kb = (size_t)k0 * 2;
        #pragma unroll
        for (int i = 0; i < 4; i++)
            load16_lds(pA[i] + kb, (char*)As + ldsoff[i]);
        __syncthreads();

        short8 af[2], bf[2];
        #pragma unroll
        for (int m = 0; m < 2; m++) af[m] = *(const short8*)((const char*)As + arow[m] + foff0);
        #pragma unroll
        for (int n = 0; n < 2; n++)
            bf[n] = *(const short8*)(wpT + (size_t)(n * 16 + lr) * 512 + k0 + lg * 8);
        #pragma unroll
        for (int m = 0; m < 2; m++)
            #pragma unroll
            for (int n = 0; n < 2; n++)
                sacc[m][n] = __builtin_amdgcn_mfma_f32_16x16x32_bf16(af[m], bf[n], sacc[m][n], 0, 0, 0);

        #pragma unroll
        for (int m = 0; m < 2; m++) af[m] = *(const short8*)((const char*)As + arow[m] + foff1);
        #pragma unroll
        for (int n = 0; n < 2; n++)
            bf[n] = *(const short8*)(wpT + (size_t)(n * 16 + lr) * 512 + k0 + 32 + lg * 8);
        #pragma unroll
        for (int m = 0; m < 2; m++)
            #pragma unroll
            for (int n = 0; n < 2; n++)
                sacc[m][n] = __builtin_amdgcn_mfma_f32_16x16x32_bf16(af[m], bf[n], sacc[m][n], 0, 0, 0);

        __syncthreads();
    }

    const float b0 = bp[lr];
    const float b1 = (lr < 4) ? bp[16 + lr] : 0.0f;
    #pragma unroll
    for (int m = 0; m < 2; m++) {
        #pragma unroll
        for (int j = 0; j < 4; j++) {
            const float v0 = sacc[m][0][j] + b0;
            const float e0 = __expf(v0);
            const float v1 = sacc[m][1][j] + b1;
            const float e1 = (lr < 4) ? __expf(v1) : 0.0f;
            float Sp = e0 + e1;
            float Tp = e0 * v0 + ((lr < 4) ? e1 * v1 : 0.0f);
            #pragma unroll
            for (int o = 1; o < 16; o <<= 1) {
                Sp += __shfl_xor(Sp, o);
                Tp += __shfl_xor(Tp, o);
            }
            const float inv = 1.0f / Sp;
            const int row = m0 + w * 32 + m * 16 + lg * 4 + j;
            probs[(size_t)row * NAA + lr] = e0 * inv;
            if (lr < 4) probs[(size_t)row * NAA + 16 + lr] = e1 * inv;
            if (lr == 0) pe[row] = logf(Sp) - Tp * inv;
        }
    }
}

// total_bias[m] = -pe[0,m]*ew + pos_bias[m]
__global__ void bias_kernel(const float* __restrict__ pe,
                            const float* __restrict__ ew,
                            const float* __restrict__ pos,
                            float* __restrict__ tb)
{
    int t = threadIdx.x;  // 512 threads
    tb[t] = -pe[t] * ew[0] + pos[t];
}

// ---------------------------------------------------------------------------
// bf16 MFMA GEMM, 256x256, BK=64, 8-phase pipeline + fragment caching.
// One barrier per LOADING phase; phases 4/8 (pure-register MFMA, LOADA=0 &
// LOADB=0) have NO leading barrier (race-check: their stage writes are
// disjoint from any half readable by one-phase laggards). 6 barriers/2 tiles.
// ---------------------------------------------------------------------------
template<int OMODE, bool BIAS, bool RELU, int RESID>
__global__ __launch_bounds__(512, 2) void mgemm7(
    const unsigned short* __restrict__ A, int lda,
    const unsigned short* __restrict__ Bt, int ldb,
    void* __restrict__ Cv, int ldc,
    const float* __restrict__ bias,
    const void* __restrict__ R, int ldr,
    int K)
{
    __shared__ __align__(16) char lds[131072];

    const int t = threadIdx.x;
    const int w = t >> 6, l = t & 63;
    const int wr = w >> 2, wc = w & 3;
    const int lg = l >> 4, lr = l & 15;

    const int gx   = gridDim.x;
    const int nwg  = gx * gridDim.y;
    const int flat = blockIdx.x + gx * blockIdx.y;
    const int cpx  = nwg >> 3;
    const int logical = (flat & 7) * cpx + (flat >> 3);
    const int m0 = (logical / gx) * 256, n0 = (logical % gx) * 256;

    f32x4 acc[8][4];
    #pragma unroll
    for (int m = 0; m < 8; m++)
        #pragma unroll
        for (int n = 0; n < 4; n++)
            acc[m][n] = (f32x4){0.f, 0.f, 0.f, 0.f};

    const int srow = t >> 3;
    const int sch  = (t & 7) ^ (srow & 7);

    auto stageA = [&](int kt, int d, int h) {
        const char* src = (const char*)A +
            ((size_t)(m0 + h * 128 + srow) * lda + sch * 8) * 2 + (size_t)kt * 128;
        char* dst = lds + d * 65536 + h * 16384 + t * 16;
        load16_lds(src, dst);
        load16_lds(src + (size_t)64 * lda * 2, dst + 8192);
    };
    auto stageB = [&](int kt, int d, int h) {
        const char* src = (const char*)Bt +
            ((size_t)(n0 + h * 128 + srow) * ldb + sch * 8) * 2 + (size_t)kt * 128;
        char* dst = lds + d * 65536 + 32768 + h * 16384 + t * 16;
        load16_lds(src, dst);
        load16_lds(src + (size_t)64 * ldb * 2, dst + 8192);
    };

    int aoff[4], boff[2], sw[2];
    #pragma unroll
    for (int mi = 0; mi < 4; mi++) aoff[mi] = (mi * 32 + wr * 16 + lr) * 128;
    #pragma unroll
    for (int ni = 0; ni < 2; ni++) boff[ni] = (ni * 64 + wc * 16 + lr) * 128;
    #pragma unroll
    for (int ks = 0; ks < 2; ks++) sw[ks] = ((ks * 4 + lg) ^ (lr & 7)) << 4;

    short8 afc[2][4];
    short8 bfc0[2][2];
    short8 bfc1[2][2];

    const int NI = K >> 7;

// BAR=1: leading barrier present. BAR=0: pure-register phase, no barrier.
#define MPHASE(D, MH, NH, LOADA, LOADB, BAR, STAGE_STMT, WAIT_STMT) do {       \
    const char* Abase_ = lds + (D) * 65536 + (MH) * 16384;                     \
    const char* Bbase_ = lds + (D) * 65536 + 32768 + (NH) * 16384;             \
    if (LOADA) {                                                               \
        _Pragma("unroll")                                                      \
        for (int ks_ = 0; ks_ < 2; ks_++)                                      \
            _Pragma("unroll")                                                  \
            for (int mi_ = 0; mi_ < 4; mi_++)                                  \
                afc[ks_][mi_] = *(const short8*)(Abase_ + aoff[mi_] + sw[ks_]);\
    }                                                                          \
    short8 (&bf_)[2][2] = (NH) ? bfc1 : bfc0;                                  \
    if (LOADB) {                                                               \
        _Pragma("unroll")                                                      \
        for (int ks_ = 0; ks_ < 2; ks_++)                                      \
            _Pragma("unroll")                                                  \
            for (int ni_ = 0; ni_ < 2; ni_++)                                  \
                bf_[ks_][ni_] = *(const short8*)(Bbase_ + boff[ni_] + sw[ks_]);\
    }                                                                          \
    STAGE_STMT;                                                                \
    WAIT_STMT;                                                                 \
    if (BAR) {                                                                 \
        __builtin_amdgcn_s_barrier();                                          \
        asm volatile("s_waitcnt lgkmcnt(0)" ::: "memory");                     \
        __builtin_amdgcn_sched_barrier(0);                                     \
    }                                                                          \
    __builtin_amdgcn_s_setprio(1);                                             \
    _Pragma("unroll")                                                          \
    for (int ks_ = 0; ks_ < 2; ks_++)                                          \
        _Pragma("unroll")                                                      \
        for (int mi_ = 0; mi_ < 4; mi_++)                                      \
            _Pragma("unroll")                                                  \
            for (int ni_ = 0; ni_ < 2; ni_++)                                  \
                acc[(MH) * 4 + mi_][(NH) * 2 + ni_] =                          \
                    __builtin_amdgcn_mfma_f32_16x16x32_bf16(                   \
                        afc[ks_][mi_], bf_[ks_][ni_],                          \
                        acc[(MH) * 4 + mi_][(NH) * 2 + ni_], 0, 0, 0);         \
    __builtin_amdgcn_s_setprio(0);                                             \
    asm volatile("" ::: "memory");                                             \
} while (0)

    stageA(0, 0, 0); stageB(0, 0, 0); stageB(0, 0, 1); stageA(0, 0, 1);
    stageA(1, 1, 0); stageB(1, 1, 0);
    asm volatile("s_waitcnt vmcnt(4)" ::: "memory");
    __builtin_amdgcn_s_barrier();
    asm volatile("" ::: "memory");

    for (int it = 0; it < NI; ++it) {
        const bool more = (it + 1 < NI);
        const int T1 = 2 * it + 1, T2 = 2 * it + 2, T3 = 2 * it + 3;

        MPHASE(0, 0, 0, 1, 1, 1, { stageB(T1, 1, 1); }, {});
        MPHASE(0, 0, 1, 0, 1, 1, { stageA(T1, 1, 1); }, {});
        MPHASE(0, 1, 0, 1, 0, 1, { if (more) stageA(T2, 0, 0); }, {});
        MPHASE(0, 1, 1, 0, 0, 0, { if (more) stageB(T2, 0, 0); },
               { if (more) { asm volatile("s_waitcnt vmcnt(4)" ::: "memory"); }
                 else      { asm volatile("s_waitcnt vmcnt(0)" ::: "memory"); } });
        MPHASE(1, 0, 0, 1, 1, 1, { if (more) stageA(T2, 0, 1); }, {});
        MPHASE(1, 0, 1, 0, 1, 1, { if (more) stageB(T2, 0, 1); }, {});
        MPHASE(1, 1, 0, 1, 0, 1, { if (more) stageA(T3, 1, 0); }, {});
        MPHASE(1, 1, 1, 0, 0, 0, { if (more) stageB(T3, 1, 0); },
               { if (more) { asm volatile("s_waitcnt vmcnt(4)" ::: "memory"); } });
    }
#undef MPHASE

    __syncthreads();   // all MFMA LDS reads done before epilogue reuses lds

    if (OMODE == 1) {
        unsigned short* cs = (unsigned short*)lds;
        #pragma unroll
        for (int nf = 0; nf < 4; nf++) {
            const int lcol = (nf >> 1) * 128 + (nf & 1) * 64 + wc * 16 + lr;
            const int col = n0 + lcol;
            const float bv = BIAS ? bias[col] : 0.0f;
            #pragma unroll
            for (int mf = 0; mf < 8; mf++) {
                const int lrow0 = (mf >> 2) * 128 + (mf & 3) * 32 + wr * 16 + lg * 4;
                #pragma unroll
                for (int j = 0; j < 4; j++) {
                    float v = acc[mf][nf][j] + bv;
                    if (RELU) v = fmaxf(v, 0.f);
                    const size_t grow = (size_t)(m0 + lrow0 + j);
                    if (RESID == 1) v += ((const float*)R)[grow * ldr + col];
                    if (RESID == 2) v += bf2f(((const unsigned short*)R)[grow * ldr + col]);
                    cs[(lrow0 + j) * 256 + lcol] = f2bf(v);
                }
            }
        }
        __syncthreads();
        unsigned short* Cp = (unsigned short*)Cv;
        #pragma unroll
        for (int i = 0; i < 16; i++) {
            const int slot = i * 512 + t;
            const int row = slot >> 5, c16 = slot & 31;
            short8 v = *(const short8*)(cs + row * 256 + c16 * 8);
            *(short8*)(Cp + (size_t)(m0 + row) * ldc + n0 + c16 * 8) = v;
        }
    } else {
        float* cf = (float*)lds;
        #pragma unroll
        for (int h = 0; h < 2; h++) {
            if (h) __syncthreads();
            #pragma unroll
            for (int nf = 0; nf < 4; nf++) {
                const int lcol = (nf >> 1) * 128 + (nf & 1) * 64 + wc * 16 + lr;
                const int col = n0 + lcol;
                const float bv = BIAS ? bias[col] : 0.0f;
                #pragma unroll
                for (int mi = 0; mi < 4; mi++) {
                    const int mf = h * 4 + mi;
                    const int lrow0 = (mf & 3) * 32 + wr * 16 + lg * 4;
                    #pragma unroll
                    for (int j = 0; j < 4; j++) {
                        float v = acc[mf][nf][j] + bv;
                        if (RELU) v = fmaxf(v, 0.f);
                        const size_t grow = (size_t)(m0 + h * 128 + lrow0 + j);
                        if (RESID == 1) v += ((const float*)R)[grow * ldr + col];
                        if (RESID == 2) v += bf2f(((const unsigned short*)R)[grow * ldr + col]);
                        cf[(lrow0 + j) * 256 + lcol] = v;
                    }
                }
            }
            __syncthreads();
            float* Cp = (float*)Cv;
            #pragma unroll
            for (int i = 0; i < 16; i++) {
                const int slot = i * 512 + t;
                const int row = slot >> 6, c4 = slot & 63;
                float4 v = *(const float4*)(cf + row * 256 + c4 * 4);
                *(float4*)(Cp + (size_t)(m0 + h * 128 + row) * ldc + n0 + c4 * 4) = v;
            }
        }
    }
}

// ---------------------------------------------------------------------------
// MFMA attention, pipelined staging (unchanged from r15/r16).
// ---------------------------------------------------------------------------
__global__ __launch_bounds__(256, 2) void attn_mfma(
    const unsigned short* __restrict__ QKV,
    const float* __restrict__ tb,
    unsigned short* __restrict__ AOb,
    float* __restrict__ lgout)
{
    const int flat = blockIdx.x + 4 * (blockIdx.y + 4 * blockIdx.z);
    const int logical = ((flat & 7) << 7) + (flat >> 3);
    const int qt = logical & 3;
    const int h  = (logical >> 2) & 3;
    const int b  = logical >> 4;
    const int t  = threadIdx.x;
    const int w  = t >> 6, l = t & 63;
    const int lr = l & 15, lg = l >> 4;
    const int qbase = qt * 128 + w * 32;

    const unsigned short* Qp = QKV;
    const unsigned short* Kp = QKV + 512;
    const unsigned short* Vp = QKV + 1024;

    __shared__ __align__(16) unsigned short Ks[2][8192];
    __shared__ __align__(16) unsigned short Vt[8192];
    __shared__ __align__(16) unsigned short Pl[8192];
    __shared__ float tbs[512];

    tbs[t] = tb[t];
    tbs[t + 256] = tb[t + 256];

    short8 qf[2][4];
    #pragma unroll
    for (int fc = 0; fc < 2; fc++) {
        const size_t qrow = (size_t)(b * LSEQ + qbase + fc * 16 + lr) * LDQKV + h * HDIM;
        #pragma unroll
        for (int ks = 0; ks < 4; ks++)
            qf[fc][ks] = *(const short8*)(Qp + qrow + ks * 32 + lg * 8);
    }

    f32x4 oacc[2][8];
    #pragma unroll
    for (int m = 0; m < 2; m++)
        #pragma unroll
        for (int n = 0; n < 8; n++)
            oacc[m][n] = (f32x4){0.f, 0.f, 0.f, 0.f};
    float lpart[2] = {0.f, 0.f};

    const float scale = 0.08838834764831845f;
    unsigned short* Plw = Pl + w * 2048;

    auto stageK = [&](int kt, int buf) {
        #pragma unroll
        for (int it = 0; it < 4; it++) {
            const int bi = it * 4 + w;
            const int r  = bi * 4 + lg;
            const int sc = lr ^ (r & 7);
            const char* src = (const char*)Kp +
                (size_t)(b * LSEQ + kt * 64 + r) * (LDQKV * 2) + h * 256 + sc * 16;
            load16_lds(src, (char*)Ks[buf] + bi * 1024);
        }
    };
    const int k0v = (l & 31) * 2;
    const int d0v = w * 32 + (l >> 5) * 16;

    stageK(0, 0);
    short8 vc0, vc1, vc2, vc3, vn0, vn1, vn2, vn3;
    {
        const size_t vrow = (size_t)(b * LSEQ + k0v) * LDQKV + h * HDIM + d0v;
        vc0 = *(const short8*)(Vp + vrow);
        vc1 = *(const short8*)(Vp + vrow + 8);
        vc2 = *(const short8*)(Vp + vrow + LDQKV);
        vc3 = *(const short8*)(Vp + vrow + LDQKV + 8);
    }

    #pragma unroll 2
    for (int kt = 0; kt < 8; ++kt) {
        asm volatile("" ::: "memory");
        __builtin_amdgcn_s_barrier();
        asm volatile("" ::: "memory");

        if (kt < 7) {
            stageK(kt + 1, (kt + 1) & 1);
            const size_t vrow = (size_t)(b * LSEQ + (kt + 1) * 64 + k0v) * LDQKV + h * HDIM + d0v;
            vn0 = *(const short8*)(Vp + vrow);
            vn1 = *(const short8*)(Vp + vrow + 8);
            vn2 = *(const short8*)(Vp + vrow + LDQKV);
            vn3 = *(const short8*)(Vp + vrow + LDQKV + 8);
        }
        asm volatile("" ::: "memory");

        #pragma unroll
        for (int j = 0; j < 16; j++) {
            const int d = d0v + j;
            unsigned short lo = (unsigned short)((j < 8) ? vc0[j] : vc1[j - 8]);
            unsigned short hi = (unsigned short)((j < 8) ? vc2[j] : vc3[j - 8]);
            unsigned int pk = (unsigned)lo | ((unsigned)hi << 16);
            const int addr = d * 128 + ((((k0v >> 3) ^ (d & 7))) << 4) + (k0v & 7) * 2;
            *(unsigned int*)((char*)Vt + addr) = pk;
        }

        if (kt < 7) { asm volatile("s_waitcnt vmcnt(8)" ::: "memory"); }
        else        { asm volatile("s_waitcnt vmcnt(0)" ::: "memory"); }
        asm volatile("s_waitcnt lgkmcnt(0)" ::: "memory");
        __builtin_amdgcn_s_barrier();
        __builtin_amdgcn_sched_barrier(0);

        const unsigned short* Ksb = Ks[kt & 1];

        f32x4 sacc[4][2];
        #pragma unroll
        for (int fm = 0; fm < 4; fm++)
            #pragma unroll
            for (int fc = 0; fc < 2; fc++)
                sacc[fm][fc] = (f32x4){0.f, 0.f, 0.f, 0.f};
        #pragma unroll
        for (int ks = 0; ks < 4; ks++) {
            short8 af[4];
            #pragma unroll
            for (int fm = 0; fm < 4; fm++) {
                const int r2 = fm * 16 + lr;
                af[fm] = *(const short8*)((const char*)Ksb +
                          r2 * 256 + (((ks * 4 + lg) ^ (lr & 7)) << 4));
            }
            #pragma unroll
            for (int fm = 0; fm < 4; fm++)
                #pragma unroll
                for (int fc = 0; fc < 2; fc++)
                    sacc[fm][fc] = __builtin_amdgcn_mfma_f32_16x16x32_bf16(
                        af[fm], qf[fc][ks], sacc[fm][fc], 0, 0, 0);
        }

        #pragma unroll
        for (int fm = 0; fm < 4; fm++) {
            #pragma unroll
            for (int fc = 0; fc < 2; fc++) {
                float p0 = sacc[fm][fc][0] * scale;
                float p1 = sacc[fm][fc][1] * scale;
                float p2 = sacc[fm][fc][2] * scale;
                float p3 = sacc[fm][fc][3] * scale;
                if (qt == 0 && w == 0 && fc == 0 && lr == 0) {
                    const int kb = kt * 64 + fm * 16 + lg * 4;
                    p0 += tbs[kb + 0]; p1 += tbs[kb + 1];
                    p2 += tbs[kb + 2]; p3 += tbs[kb + 3];
                }
                p0 = __expf(p0); p1 = __expf(p1);
                p2 = __expf(p2); p3 = __expf(p3);
                lpart[fc] += (p0 + p1) + (p2 + p3);
                const int rq = fc * 16 + lr;
                const int chunk = fm * 2 + (lg >> 1);
                const int addr = rq * 128 + ((chunk ^ (rq & 7)) << 4) + (lg & 1) * 8;
                unsigned int lo = (unsigned)f2bf(p0) | ((unsigned)f2bf(p1) << 16);
                unsigned int hi = (unsigned)f2bf(p2) | ((unsigned)f2bf(p3) << 16);
                *(uint2*)((char*)Plw + addr) = make_uint2(lo, hi);
            }
        }

        #pragma unroll
        for (int ks2 = 0; ks2 < 2; ks2++) {
            short8 pf[2];
            #pragma unroll
            for (int fm2 = 0; fm2 < 2; fm2++) {
                const int rq2 = fm2 * 16 + lr;
                pf[fm2] = *(const short8*)((const char*)Plw +
                           rq2 * 128 + (((ks2 * 4 + lg) ^ (rq2 & 7)) << 4));
            }
            #pragma unroll
            for (int fn = 0; fn < 8; fn++) {
                const int d = fn * 16 + lr;
                short8 vf = *(const short8*)((const char*)Vt +
                             d * 128 + (((ks2 * 4 + lg) ^ (d & 7)) << 4));
                #pragma unroll
                for (int fm2 = 0; fm2 < 2; fm2++)
                    oacc[fm2][fn] = __builtin_amdgcn_mfma_f32_16x16x32_bf16(
                        pf[fm2], vf, oacc[fm2][fn], 0, 0, 0);
            }
        }

        vc0 = vn0; vc1 = vn1; vc2 = vn2; vc3 = vn3;
    }

    float l0 = lpart[0], l1 = lpart[1];
    l0 += __shfl_xor(l0, 16); l0 += __shfl_xor(l0, 32);
    l1 += __shfl_xor(l1, 16); l1 += __shfl_xor(l1, 32);
    float* lw = (float*)Plw;
    if (lg == 0) { lw[lr] = l0; lw[16 + lr] = l1; }
    if (h == 0 && lg == 0) {
        lgout[b * LSEQ + qbase + lr]      = l0;
        lgout[b * LSEQ + qbase + 16 + lr] = l1;
    }
    __builtin_amdgcn_s_waitcnt(0);

    #pragma unroll
    for (int fm2 = 0; fm2 < 2; fm2++) {
        float linv[4];
        #pragma unroll
        for (int j = 0; j < 4; j++)
            linv[j] = 1.0f / lw[fm2 * 16 + lg * 4 + j];
        #pragma unroll
        for (int fn = 0; fn < 8; fn++) {
            const int d = fn * 16 + lr;
            #pragma unroll
            for (int j = 0; j < 4; j++) {
                const int q = qbase + fm2 * 16 + lg * 4 + j;
                AOb[(size_t)(b * LSEQ + q) * SDIM + h * HDIM + d] =
                    f2bf(oacc[fm2][fn][j] * linv[j]);
            }
        }
    }
}

// ---------------------------------------------------------------------------
// sw0: recompute h=0 scores, NORMALIZED W0 fp32 (r16 double-buffered).
// ---------------------------------------------------------------------------
__global__ __launch_bounds__(256, 2) void sw0_kernel(
    const unsigned short* __restrict__ QKV,
    const float* __restrict__ tb,
    const float* __restrict__ lsum,
    float* __restrict__ W0)
{
    const int flat = blockIdx.x + 4 * blockIdx.y;
    const int logical = ((flat & 7) << 5) + (flat >> 3);
    const int qt = logical & 3;
    const int b  = logical >> 2;
    const int t  = threadIdx.x;
    const int w  = t >> 6, l = t & 63;
    const int lr = l & 15, lg = l >> 4;
    const int qbase = qt * 128 + w * 32;

    const unsigned short* Qp = QKV;
    const unsigned short* Kp = QKV + 512;

    __shared__ __align__(16) unsigned short Ks[2][8192];
    __shared__ __align__(16) float Sc[4][32][68];

    short8 qf[2][4];
    #pragma unroll
    for (int fc = 0; fc < 2; fc++) {
        const size_t qrow = (size_t)(b * LSEQ + qbase + fc * 16 + lr) * LDQKV;
        #pragma unroll
        for (int ks = 0; ks < 4; ks++)
            qf[fc][ks] = *(const short8*)(Qp + qrow + ks * 32 + lg * 8);
    }

    float linv[2];
    linv[0] = 1.0f / lsum[b * LSEQ + qbase + lr];
    linv[1] = 1.0f / lsum[b * LSEQ + qbase + 16 + lr];

    const float scale = 0.08838834764831845f;

    auto stageK = [&](int kt, int buf) {
        #pragma unroll
        for (int it = 0; it < 4; it++) {
            const int bi = it * 4 + w;
            const int r  = bi * 4 + lg;
            const int sc = lr ^ (r & 7);
            const char* src = (const char*)Kp +
                (size_t)(b * LSEQ + kt * 64 + r) * (LDQKV * 2) + sc * 16;
            load16_lds(src, (char*)Ks[buf] + bi * 1024);
        }
    };

    stageK(0, 0);

    for (int kt = 0; kt < 8; ++kt) {
        asm volatile("" ::: "memory");
        __builtin_amdgcn_s_barrier();
        asm volatile("" ::: "memory");

        if (kt < 7) stageK(kt + 1, (kt + 1) & 1);

        if (kt < 7) { asm volatile("s_waitcnt vmcnt(4)" ::: "memory"); }
        else        { asm volatile("s_waitcnt vmcnt(0)" ::: "memory"); }
        __builtin_amdgcn_s_barrier();
        __builtin_amdgcn_sched_barrier(0);

        const unsigned short* Ksb = Ks[kt & 1];

        f32x4 sacc[4][2];
        #pragma unroll
        for (int fm = 0; fm < 4; fm++)
            #pragma unroll
            for (int fc = 0; fc < 2; fc++)
                sacc[fm][fc] = (f32x4){0.f, 0.f, 0.f, 0.f};
        #pragma unroll
        for (int ks = 0; ks < 4; ks++) {
            short8 af[4];
            #pragma unroll
            for (int fm = 0; fm < 4; fm++) {
                const int r2 = fm * 16 + lr;
                af[fm] = *(const short8*)((const char*)Ksb +
                          r2 * 256 + (((ks * 4 + lg) ^ (lr & 7)) << 4));
            }
            #pragma unroll
            for (int fm = 0; fm < 4; fm++)
                #pragma unroll
                for (int fc = 0; fc < 2; fc++)
                    sacc[fm][fc] = __builtin_amdgcn_mfma_f32_16x16x32_bf16(
                        af[fm], qf[fc][ks], sacc[fm][fc], 0, 0, 0);
        }

        #pragma unroll
        for (int fm = 0; fm < 4; fm++) {
            #pragma unroll
            for (int fc = 0; fc < 2; fc++) {
                float p0 = sacc[fm][fc][0] * scale;
                float p1 = sacc[fm][fc][1] * scale;
                float p2 = sacc[fm][fc][2] * scale;
                float p3 = sacc[fm][fc][3] * scale;
                if (qt == 0 && w == 0 && fc == 0 && lr == 0) {
                    const int kb = kt * 64 + fm * 16 + lg * 4;
                    p0 += tb[kb + 0]; p1 += tb[kb + 1];
                    p2 += tb[kb + 2]; p3 += tb[kb + 3];
                }
                p0 = __expf(p0) * linv[fc]; p1 = __expf(p1) * linv[fc];
                p2 = __expf(p2) * linv[fc]; p3 = __expf(p3) * linv[fc];
                *(float4*)&Sc[w][fc * 16 + lr][fm * 16 + lg * 4] =
                    make_float4(p0, p1, p2, p3);
            }
        }

        #pragma unroll
        for (int i = 0; i < 8; i++) {
            const int row = i * 4 + lg;
            float4 v = *(const float4*)&Sc[w][row][lr * 4];
            *(float4*)(W0 + (size_t)(b * LSEQ + qbase + row) * LSEQ +
                       kt * 64 + lr * 4) = v;
        }
    }
}

// ---------------------------------------------------------------------------
extern "C" void kernel_launch(void* const* d_in, const int* in_sizes, int n_in,
                              void* d_out, int out_size, void* d_ws, size_t ws_size,
                              hipStream_t stream)
{
    const float* s   = (const float*)d_in[0];
    const float* z   = (const float*)d_in[1];
    const float* wq  = (const float*)d_in[2];
    const float* bq  = (const float*)d_in[3];
    const float* wk  = (const float*)d_in[4];
    const float* bk  = (const float*)d_in[5];
    const float* wv  = (const float*)d_in[6];
    const float* bv  = (const float*)d_in[7];
    const float* wo  = (const float*)d_in[8];
    const float* bo  = (const float*)d_in[9];
    const float* wp  = (const float*)d_in[10];
    const float* bp  = (const float*)d_in[11];
    const float* pos = (const float*)d_in[12];
    const float* ew  = (const float*)d_in[13];
    const float* lng = (const float*)d_in[14];
    const float* lnb = (const float*)d_in[15];
    const float* w1  = (const float*)d_in[16];
    const float* b1  = (const float*)d_in[17];
    const float* w2  = (const float*)d_in[18];
    const float* b2  = (const float*)d_in[19];

    float* out = (float*)d_out;
    const size_t oz  = (size_t)NROWS * SDIM;
    const size_t ow  = oz + (size_t)NROWS * 64;
    const size_t ope = ow + (size_t)NROWS * LSEQ;
    const size_t opr = ope + (size_t)NROWS;

    // workspace layout (bytes)
    char* wsb = (char*)d_ws;
    unsigned short* QKV = (unsigned short*)(wsb);
    unsigned short* F   = (unsigned short*)(wsb);
    unsigned short* Xb  = (unsigned short*)(wsb + 100663296);
    unsigned short* s2b = (unsigned short*)(wsb + 134217728);
    unsigned short* hb  = (unsigned short*)(wsb + 167772160);
    unsigned short* wqkvt = (unsigned short*)(wsb + 234881024);
    unsigned short* wot = wqkvt + 786432;
    unsigned short* w1t = wqkvt + 1048576;    // [2048][512]
    unsigned short* w2t = wqkvt + 2097152;    // [512][2048]
    unsigned short* wpT = wqkvt + 3145728;    // [32][512]
    float* bqkv = (float*)(wsb + 234881024 + 6324224);
    float* tb   = bqkv + 1536;
    float* lgv  = tb + 512;

    // 0. weight prep
    wtrans<<<dim3(16, 16), 256, 0, stream>>>(wq, wqkvt, 512, 512);
    wtrans<<<dim3(16, 16), 256, 0, stream>>>(wk, wqkvt + 262144, 512, 512);
    wtrans<<<dim3(16, 16), 256, 0, stream>>>(wv, wqkvt + 524288, 512, 512);
    wtrans<<<dim3(16, 16), 256, 0, stream>>>(wo, wot, 512, 512);
    wtrans<<<dim3(64, 16), 256, 0, stream>>>(w1, w1t, 512, 2048);
    wtrans<<<dim3(16, 64), 256, 0, stream>>>(w2, w2t, 2048, 512);
    wptrans<<<64, 256, 0, stream>>>(wp, wpT);
    bpack<<<1, 512, 0, stream>>>(bq, bk, bv, bqkv);

    // 1. LN(s) -> bf16 Xb (wave-per-row)
    ln_kernel<0, false><<<NROWS / 4, 256, 0, stream>>>(s, Xb, nullptr, nullptr);

    // 1b. profile softmax + entropy (MFMA)
    profile_kernel<<<256, 256, 0, stream>>>(Xb, wpT, bp, out + opr, out + ope);

    // 2. total bias from batch-0 entropy
    bias_kernel<<<1, 512, 0, stream>>>(out + ope, ew, pos, tb);

    // 3. fused QKV projection -> QKV bf16 [32768][1536]
    mgemm7<1, true, false, 0><<<dim3(6, 128), 512, 0, stream>>>(
        Xb, 512, wqkvt, 512, QKV, LDQKV, bqkv, nullptr, 0, 512);

    // 4. MFMA attention -> attn_out bf16 (Xb) + rowsums
    attn_mfma<<<dim3(4, NHEAD, BATCH), 256, 0, stream>>>(
        QKV, tb, Xb, lgv);

    // 4b. head-0 normalized attention weights (fp32)
    sw0_kernel<<<dim3(4, BATCH), 256, 0, stream>>>(QKV, tb, lgv, out + ow);

    // 5. s2 = s + attn_out @ wo + bo  -> bf16 s2b
    mgemm7<1, true, false, 1><<<dim3(2, 128), 512, 0, stream>>>(
        Xb, 512, wot, 512, s2b, 512, bo, s, 512, 512);

    // 6. h = LN(s2)*g + b -> bf16 (bf16 input)
    ln_kernel<1, true><<<NROWS / 4, 256, 0, stream>>>(s2b, hb, lng, lnb);

    // 7. FFN1: F = relu(h @ w1 + b1), bf16 [32768][2048]
    mgemm7<1, true, true, 0><<<dim3(8, 128), 512, 0, stream>>>(
        hb, 512, w1t, 512, F, 2048, b1, nullptr, 0, 512);

    // 8. FFN2: out0 = F @ w2 + b2 + s2b
    mgemm7<0, true, false, 2><<<dim3(2, 128), 512, 0, stream>>>(
        F, 2048, w2t, 2048, out, 512, b2, s2b, 512, 2048);

    // 9. z passthrough
    hipMemcpyAsync(out + oz, z, (size_t)NROWS * 64 * sizeof(float),
                   hipMemcpyDeviceToDevice, stream);
}

// Round 18
// 422.749 us; speedup vs baseline: 1.0004x; 1.0004x over previous
//
#include <hip/hip_runtime.h>
#include <hip/hip_bf16.h>
#include <math.h>

// Problem constants
#define SDIM 512
#define BATCH 64
#define LSEQ 512
#define NHEAD 4
#define HDIM 128
#define NAA 20
#define NROWS (BATCH * LSEQ)   // 32768
#define LDQKV 1536

typedef __attribute__((ext_vector_type(8))) short short8;
typedef __attribute__((ext_vector_type(4))) float f32x4;

__device__ __forceinline__ unsigned short f2bf(float f) {
    unsigned int x = __float_as_uint(f);
    unsigned int r = (x + 0x7fffu + ((x >> 16) & 1u)) >> 16;  // RNE
    return (unsigned short)r;
}
__device__ __forceinline__ float bf2f(unsigned short u) {
    return __uint_as_float((unsigned int)u << 16);
}

__device__ __forceinline__ void load16_lds(const void* g, void* lds) {
    __builtin_amdgcn_global_load_lds(
        (const __attribute__((address_space(1))) unsigned int*)g,
        (__attribute__((address_space(3))) unsigned int*)lds, 16, 0, 0);
}

// ---------------------------------------------------------------------------
// Weight transpose + bf16 convert: W[K][N] fp32 -> Wt[N][K] bf16
// ---------------------------------------------------------------------------
__global__ __launch_bounds__(256) void wtrans(
    const float* __restrict__ W, unsigned short* __restrict__ Wt, int K, int N)
{
    __shared__ float tile[32][33];
    const int t = threadIdx.x, tx = t & 31, ty = t >> 5;
    const int n0 = blockIdx.x * 32, k0 = blockIdx.y * 32;
    #pragma unroll
    for (int p = 0; p < 4; p++)
        tile[ty + p * 8][tx] = W[(size_t)(k0 + ty + p * 8) * N + n0 + tx];
    __syncthreads();
    #pragma unroll
    for (int p = 0; p < 4; p++)
        Wt[(size_t)(n0 + ty + p * 8) * K + k0 + tx] = f2bf(tile[tx][ty + p * 8]);
}

// wp [512][20] fp32 -> wpT [32][512] bf16, rows 20..31 zero
__global__ __launch_bounds__(256) void wptrans(
    const float* __restrict__ wp, unsigned short* __restrict__ wpT)
{
    const int g = blockIdx.x * 256 + threadIdx.x;
    const int k = g & 511, j = g >> 9;
    float v = (j < NAA) ? wp[(size_t)k * NAA + j] : 0.0f;
    wpT[(size_t)j * 512 + k] = f2bf(v);
}

// pack bq|bk|bv into one 1536 vector
__global__ void bpack(const float* __restrict__ bq, const float* __restrict__ bk,
                      const float* __restrict__ bv, float* __restrict__ bqkv)
{
    int t = threadIdx.x;  // 512
    bqkv[t] = bq[t]; bqkv[512 + t] = bk[t]; bqkv[1024 + t] = bv[t];
}

// ---------------------------------------------------------------------------
// LayerNorm: one WAVE per row, no LDS/barriers. INMODE 0=fp32 in, 1=bf16 in.
// ---------------------------------------------------------------------------
template<int INMODE, bool AFFINE>
__global__ __launch_bounds__(256) void ln_kernel(
    const void* __restrict__ inp, unsigned short* __restrict__ out,
    const float* __restrict__ gamma, const float* __restrict__ beta)
{
    const int w = threadIdx.x >> 6, l = threadIdx.x & 63;
    const int r = blockIdx.x * 4 + w;

    float x[8];
    if (INMODE == 0) {
        const float* row = (const float*)inp + (size_t)r * SDIM;
        float4 a = *(const float4*)(row + l * 4);
        float4 b = *(const float4*)(row + 256 + l * 4);
        x[0] = a.x; x[1] = a.y; x[2] = a.z; x[3] = a.w;
        x[4] = b.x; x[5] = b.y; x[6] = b.z; x[7] = b.w;
    } else {
        const unsigned short* row = (const unsigned short*)inp + (size_t)r * SDIM;
        uint2 a = *(const uint2*)(row + l * 4);
        uint2 b = *(const uint2*)(row + 256 + l * 4);
        x[0] = bf2f((unsigned short)(a.x & 0xffff)); x[1] = bf2f((unsigned short)(a.x >> 16));
        x[2] = bf2f((unsigned short)(a.y & 0xffff)); x[3] = bf2f((unsigned short)(a.y >> 16));
        x[4] = bf2f((unsigned short)(b.x & 0xffff)); x[5] = bf2f((unsigned short)(b.x >> 16));
        x[6] = bf2f((unsigned short)(b.y & 0xffff)); x[7] = bf2f((unsigned short)(b.y >> 16));
    }

    float sum = 0.f, sq = 0.f;
    #pragma unroll
    for (int i = 0; i < 8; i++) { sum += x[i]; sq += x[i] * x[i]; }
    #pragma unroll
    for (int o = 1; o < 64; o <<= 1) {
        sum += __shfl_xor(sum, o);
        sq  += __shfl_xor(sq, o);
    }
    const float mean = sum * (1.0f / SDIM);
    const float var  = sq * (1.0f / SDIM) - mean * mean;
    const float inv  = rsqrtf(var + 1e-5f);

    float y[8];
    if (AFFINE) {
        float4 g0 = *(const float4*)(gamma + l * 4);
        float4 g1 = *(const float4*)(gamma + 256 + l * 4);
        float4 b0 = *(const float4*)(beta + l * 4);
        float4 b1 = *(const float4*)(beta + 256 + l * 4);
        y[0] = (x[0]-mean)*inv*g0.x + b0.x; y[1] = (x[1]-mean)*inv*g0.y + b0.y;
        y[2] = (x[2]-mean)*inv*g0.z + b0.z; y[3] = (x[3]-mean)*inv*g0.w + b0.w;
        y[4] = (x[4]-mean)*inv*g1.x + b1.x; y[5] = (x[5]-mean)*inv*g1.y + b1.y;
        y[6] = (x[6]-mean)*inv*g1.z + b1.z; y[7] = (x[7]-mean)*inv*g1.w + b1.w;
    } else {
        #pragma unroll
        for (int i = 0; i < 8; i++) y[i] = (x[i] - mean) * inv;
    }

    unsigned short* orow = out + (size_t)r * SDIM;
    uint2 p0, p1;
    p0.x = (unsigned)f2bf(y[0]) | ((unsigned)f2bf(y[1]) << 16);
    p0.y = (unsigned)f2bf(y[2]) | ((unsigned)f2bf(y[3]) << 16);
    p1.x = (unsigned)f2bf(y[4]) | ((unsigned)f2bf(y[5]) << 16);
    p1.y = (unsigned)f2bf(y[6]) | ((unsigned)f2bf(y[7]) << 16);
    *(uint2*)(orow + l * 4)       = p0;
    *(uint2*)(orow + 256 + l * 4) = p1;
}

// ---------------------------------------------------------------------------
// Profile kernel: logits = s_ln(bf16) @ wpT^T + bp, softmax+entropy epilogue.
// ---------------------------------------------------------------------------
__global__ __launch_bounds__(256) void profile_kernel(
    const unsigned short* __restrict__ A,
    const unsigned short* __restrict__ wpT,
    const float* __restrict__ bp,
    float* __restrict__ probs,
    float* __restrict__ pe)
{
    __shared__ __align__(16) unsigned short As[128 * 64];

    const int t = threadIdx.x;
    const int w = t >> 6, l = t & 63;
    const int lr = l & 15, lg = l >> 4;
    const int m0 = blockIdx.x * 128;

    f32x4 sacc[2][2];
    #pragma unroll
    for (int m = 0; m < 2; m++)
        #pragma unroll
        for (int n = 0; n < 2; n++)
            sacc[m][n] = (f32x4){0.f, 0.f, 0.f, 0.f};

    const int srow  = l >> 3;
    const int swz16 = ((l & 7) ^ srow) << 4;
    const char* pA[4];
    unsigned ldsoff[4];
    #pragma unroll
    for (int i = 0; i < 4; i++) {
        const int row = (w * 4 + i) * 8 + srow;
        pA[i] = (const char*)A + (size_t)(m0 + row) * 1024 + swz16;
        ldsoff[i] = (unsigned)(w * 4 + i) * 1024;
    }

    const int rsw   = (lr & 7) << 4;
    const int foff0 = (lg * 16) ^ rsw;
    const int foff1 = (64 + lg * 16) ^ rsw;
    int arow[2];
    #pragma unroll
    for (int m = 0; m < 2; m++) arow[m] = (w * 32 + m * 16 + lr) * 128;

    for (int k0 = 0; k0 < 512; k0 += 64) {
        const size_t kb = (size_t)k0 * 2;
        #pragma unroll
        for (int i = 0; i < 4; i++)
            load16_lds(pA[i] + kb, (char*)As + ldsoff[i]);
        __syncthreads();

        short8 af[2], bf[2];
        #pragma unroll
        for (int m = 0; m < 2; m++) af[m] = *(const short8*)((const char*)As + arow[m] + foff0);
        #pragma unroll
        for (int n = 0; n < 2; n++)
            bf[n] = *(const short8*)(wpT + (size_t)(n * 16 + lr) * 512 + k0 + lg * 8);
        #pragma unroll
        for (int m = 0; m < 2; m++)
            #pragma unroll
            for (int n = 0; n < 2; n++)
                sacc[m][n] = __builtin_amdgcn_mfma_f32_16x16x32_bf16(af[m], bf[n], sacc[m][n], 0, 0, 0);

        #pragma unroll
        for (int m = 0; m < 2; m++) af[m] = *(const short8*)((const char*)As + arow[m] + foff1);
        #pragma unroll
        for (int n = 0; n < 2; n++)
            bf[n] = *(const short8*)(wpT + (size_t)(n * 16 + lr) * 512 + k0 + 32 + lg * 8);
        #pragma unroll
        for (int m = 0; m < 2; m++)
            #pragma unroll
            for (int n = 0; n < 2; n++)
                sacc[m][n] = __builtin_amdgcn_mfma_f32_16x16x32_bf16(af[m], bf[n], sacc[m][n], 0, 0, 0);

        __syncthreads();
    }

    const float b0 = bp[lr];
    const float b1 = (lr < 4) ? bp[16 + lr] : 0.0f;
    #pragma unroll
    for (int m = 0; m < 2; m++) {
        #pragma unroll
        for (int j = 0; j < 4; j++) {
            const float v0 = sacc[m][0][j] + b0;
            const float e0 = __expf(v0);
            const float v1 = sacc[m][1][j] + b1;
            const float e1 = (lr < 4) ? __expf(v1) : 0.0f;
            float Sp = e0 + e1;
            float Tp = e0 * v0 + ((lr < 4) ? e1 * v1 : 0.0f);
            #pragma unroll
            for (int o = 1; o < 16; o <<= 1) {
                Sp += __shfl_xor(Sp, o);
                Tp += __shfl_xor(Tp, o);
            }
            const float inv = 1.0f / Sp;
            const int row = m0 + w * 32 + m * 16 + lg * 4 + j;
            probs[(size_t)row * NAA + lr] = e0 * inv;
            if (lr < 4) probs[(size_t)row * NAA + 16 + lr] = e1 * inv;
            if (lr == 0) pe[row] = logf(Sp) - Tp * inv;
        }
    }
}

// total_bias[m] = -pe[0,m]*ew + pos_bias[m]
__global__ void bias_kernel(const float* __restrict__ pe,
                            const float* __restrict__ ew,
                            const float* __restrict__ pos,
                            float* __restrict__ tb)
{
    int t = threadIdx.x;  // 512 threads
    tb[t] = -pe[t] * ew[0] + pos[t];
}

// ---------------------------------------------------------------------------
// bf16 MFMA GEMM, 256x256, BK=64, 8-phase pipeline + fragment caching.
// vs r17: removed the blanket post-barrier lgkmcnt(0)+sched_barrier(0) —
// fragment reads are plain loads on data published >=1 barrier earlier, so
// the compiler's fine-grained lgkmcnt interleave (guide §5) is sufficient
// and lets MFMAs start before all 12 reads drain. MFMAs are register-only,
// so their position relative to the barrier cannot affect results.
// ---------------------------------------------------------------------------
template<int OMODE, bool BIAS, bool RELU, int RESID>
__global__ __launch_bounds__(512, 2) void mgemm7(
    const unsigned short* __restrict__ A, int lda,
    const unsigned short* __restrict__ Bt, int ldb,
    void* __restrict__ Cv, int ldc,
    const float* __restrict__ bias,
    const void* __restrict__ R, int ldr,
    int K)
{
    __shared__ __align__(16) char lds[131072];

    const int t = threadIdx.x;
    const int w = t >> 6, l = t & 63;
    const int wr = w >> 2, wc = w & 3;
    const int lg = l >> 4, lr = l & 15;

    const int gx   = gridDim.x;
    const int nwg  = gx * gridDim.y;
    const int flat = blockIdx.x + gx * blockIdx.y;
    const int cpx  = nwg >> 3;
    const int logical = (flat & 7) * cpx + (flat >> 3);
    const int m0 = (logical / gx) * 256, n0 = (logical % gx) * 256;

    f32x4 acc[8][4];
    #pragma unroll
    for (int m = 0; m < 8; m++)
        #pragma unroll
        for (int n = 0; n < 4; n++)
            acc[m][n] = (f32x4){0.f, 0.f, 0.f, 0.f};

    const int srow = t >> 3;
    const int sch  = (t & 7) ^ (srow & 7);

    auto stageA = [&](int kt, int d, int h) {
        const char* src = (const char*)A +
            ((size_t)(m0 + h * 128 + srow) * lda + sch * 8) * 2 + (size_t)kt * 128;
        char* dst = lds + d * 65536 + h * 16384 + t * 16;
        load16_lds(src, dst);
        load16_lds(src + (size_t)64 * lda * 2, dst + 8192);
    };
    auto stageB = [&](int kt, int d, int h) {
        const char* src = (const char*)Bt +
            ((size_t)(n0 + h * 128 + srow) * ldb + sch * 8) * 2 + (size_t)kt * 128;
        char* dst = lds + d * 65536 + 32768 + h * 16384 + t * 16;
        load16_lds(src, dst);
        load16_lds(src + (size_t)64 * ldb * 2, dst + 8192);
    };

    int aoff[4], boff[2], sw[2];
    #pragma unroll
    for (int mi = 0; mi < 4; mi++) aoff[mi] = (mi * 32 + wr * 16 + lr) * 128;
    #pragma unroll
    for (int ni = 0; ni < 2; ni++) boff[ni] = (ni * 64 + wc * 16 + lr) * 128;
    #pragma unroll
    for (int ks = 0; ks < 2; ks++) sw[ks] = ((ks * 4 + lg) ^ (lr & 7)) << 4;

    short8 afc[2][4];
    short8 bfc0[2][2];
    short8 bfc1[2][2];

    const int NI = K >> 7;

// BAR=1: leading barrier present. BAR=0: pure-register phase, no barrier.
#define MPHASE(D, MH, NH, LOADA, LOADB, BAR, STAGE_STMT, WAIT_STMT) do {       \
    const char* Abase_ = lds + (D) * 65536 + (MH) * 16384;                     \
    const char* Bbase_ = lds + (D) * 65536 + 32768 + (NH) * 16384;             \
    if (LOADA) {                                                               \
        _Pragma("unroll")                                                      \
        for (int ks_ = 0; ks_ < 2; ks_++)                                      \
            _Pragma("unroll")                                                  \
            for (int mi_ = 0; mi_ < 4; mi_++)                                  \
                afc[ks_][mi_] = *(const short8*)(Abase_ + aoff[mi_] + sw[ks_]);\
    }                                                                          \
    short8 (&bf_)[2][2] = (NH) ? bfc1 : bfc0;                                  \
    if (LOADB) {                                                               \
        _Pragma("unroll")                                                      \
        for (int ks_ = 0; ks_ < 2; ks_++)                                      \
            _Pragma("unroll")                                                  \
            for (int ni_ = 0; ni_ < 2; ni_++)                                  \
                bf_[ks_][ni_] = *(const short8*)(Bbase_ + boff[ni_] + sw[ks_]);\
    }                                                                          \
    STAGE_STMT;                                                                \
    WAIT_STMT;                                                                 \
    if (BAR) {                                                                 \
        __builtin_amdgcn_s_barrier();                                          \
    }                                                                          \
    __builtin_amdgcn_s_setprio(1);                                             \
    _Pragma("unroll")                                                          \
    for (int ks_ = 0; ks_ < 2; ks_++)                                          \
        _Pragma("unroll")                                                      \
        for (int mi_ = 0; mi_ < 4; mi_++)                                      \
            _Pragma("unroll")                                                  \
            for (int ni_ = 0; ni_ < 2; ni_++)                                  \
                acc[(MH) * 4 + mi_][(NH) * 2 + ni_] =                          \
                    __builtin_amdgcn_mfma_f32_16x16x32_bf16(                   \
                        afc[ks_][mi_], bf_[ks_][ni_],                          \
                        acc[(MH) * 4 + mi_][(NH) * 2 + ni_], 0, 0, 0);         \
    __builtin_amdgcn_s_setprio(0);                                             \
    asm volatile("" ::: "memory");                                             \
} while (0)

    stageA(0, 0, 0); stageB(0, 0, 0); stageB(0, 0, 1); stageA(0, 0, 1);
    stageA(1, 1, 0); stageB(1, 1, 0);
    asm volatile("s_waitcnt vmcnt(4)" ::: "memory");
    __builtin_amdgcn_s_barrier();
    asm volatile("" ::: "memory");

    for (int it = 0; it < NI; ++it) {
        const bool more = (it + 1 < NI);
        const int T1 = 2 * it + 1, T2 = 2 * it + 2, T3 = 2 * it + 3;

        MPHASE(0, 0, 0, 1, 1, 1, { stageB(T1, 1, 1); }, {});
        MPHASE(0, 0, 1, 0, 1, 1, { stageA(T1, 1, 1); }, {});
        MPHASE(0, 1, 0, 1, 0, 1, { if (more) stageA(T2, 0, 0); }, {});
        MPHASE(0, 1, 1, 0, 0, 0, { if (more) stageB(T2, 0, 0); },
               { if (more) { asm volatile("s_waitcnt vmcnt(4)" ::: "memory"); }
                 else      { asm volatile("s_waitcnt vmcnt(0)" ::: "memory"); } });
        MPHASE(1, 0, 0, 1, 1, 1, { if (more) stageA(T2, 0, 1); }, {});
        MPHASE(1, 0, 1, 0, 1, 1, { if (more) stageB(T2, 0, 1); }, {});
        MPHASE(1, 1, 0, 1, 0, 1, { if (more) stageA(T3, 1, 0); }, {});
        MPHASE(1, 1, 1, 0, 0, 0, { if (more) stageB(T3, 1, 0); },
               { if (more) { asm volatile("s_waitcnt vmcnt(4)" ::: "memory"); } });
    }
#undef MPHASE

    __syncthreads();   // all MFMA LDS reads done before epilogue reuses lds

    if (OMODE == 1) {
        unsigned short* cs = (unsigned short*)lds;
        #pragma unroll
        for (int nf = 0; nf < 4; nf++) {
            const int lcol = (nf >> 1) * 128 + (nf & 1) * 64 + wc * 16 + lr;
            const int col = n0 + lcol;
            const float bv = BIAS ? bias[col] : 0.0f;
            #pragma unroll
            for (int mf = 0; mf < 8; mf++) {
                const int lrow0 = (mf >> 2) * 128 + (mf & 3) * 32 + wr * 16 + lg * 4;
                #pragma unroll
                for (int j = 0; j < 4; j++) {
                    float v = acc[mf][nf][j] + bv;
                    if (RELU) v = fmaxf(v, 0.f);
                    const size_t grow = (size_t)(m0 + lrow0 + j);
                    if (RESID == 1) v += ((const float*)R)[grow * ldr + col];
                    if (RESID == 2) v += bf2f(((const unsigned short*)R)[grow * ldr + col]);
                    cs[(lrow0 + j) * 256 + lcol] = f2bf(v);
                }
            }
        }
        __syncthreads();
        unsigned short* Cp = (unsigned short*)Cv;
        #pragma unroll
        for (int i = 0; i < 16; i++) {
            const int slot = i * 512 + t;
            const int row = slot >> 5, c16 = slot & 31;
            short8 v = *(const short8*)(cs + row * 256 + c16 * 8);
            *(short8*)(Cp + (size_t)(m0 + row) * ldc + n0 + c16 * 8) = v;
        }
    } else {
        float* cf = (float*)lds;
        #pragma unroll
        for (int h = 0; h < 2; h++) {
            if (h) __syncthreads();
            #pragma unroll
            for (int nf = 0; nf < 4; nf++) {
                const int lcol = (nf >> 1) * 128 + (nf & 1) * 64 + wc * 16 + lr;
                const int col = n0 + lcol;
                const float bv = BIAS ? bias[col] : 0.0f;
                #pragma unroll
                for (int mi = 0; mi < 4; mi++) {
                    const int mf = h * 4 + mi;
                    const int lrow0 = (mf & 3) * 32 + wr * 16 + lg * 4;
                    #pragma unroll
                    for (int j = 0; j < 4; j++) {
                        float v = acc[mf][nf][j] + bv;
                        if (RELU) v = fmaxf(v, 0.f);
                        const size_t grow = (size_t)(m0 + h * 128 + lrow0 + j);
                        if (RESID == 1) v += ((const float*)R)[grow * ldr + col];
                        if (RESID == 2) v += bf2f(((const unsigned short*)R)[grow * ldr + col]);
                        cf[(lrow0 + j) * 256 + lcol] = v;
                    }
                }
            }
            __syncthreads();
            float* Cp = (float*)Cv;
            #pragma unroll
            for (int i = 0; i < 16; i++) {
                const int slot = i * 512 + t;
                const int row = slot >> 6, c4 = slot & 63;
                float4 v = *(const float4*)(cf + row * 256 + c4 * 4);
                *(float4*)(Cp + (size_t)(m0 + h * 128 + row) * ldc + n0 + c4 * 4) = v;
            }
        }
    }
}

// ---------------------------------------------------------------------------
// MFMA attention, pipelined staging (unchanged from r15/r16).
// ---------------------------------------------------------------------------
__global__ __launch_bounds__(256, 2) void attn_mfma(
    const unsigned short* __restrict__ QKV,
    const float* __restrict__ tb,
    unsigned short* __restrict__ AOb,
    float* __restrict__ lgout)
{
    const int flat = blockIdx.x + 4 * (blockIdx.y + 4 * blockIdx.z);
    const int logical = ((flat & 7) << 7) + (flat >> 3);
    const int qt = logical & 3;
    const int h  = (logical >> 2) & 3;
    const int b  = logical >> 4;
    const int t  = threadIdx.x;
    const int w  = t >> 6, l = t & 63;
    const int lr = l & 15, lg = l >> 4;
    const int qbase = qt * 128 + w * 32;

    const unsigned short* Qp = QKV;
    const unsigned short* Kp = QKV + 512;
    const unsigned short* Vp = QKV + 1024;

    __shared__ __align__(16) unsigned short Ks[2][8192];
    __shared__ __align__(16) unsigned short Vt[8192];
    __shared__ __align__(16) unsigned short Pl[8192];
    __shared__ float tbs[512];

    tbs[t] = tb[t];
    tbs[t + 256] = tb[t + 256];

    short8 qf[2][4];
    #pragma unroll
    for (int fc = 0; fc < 2; fc++) {
        const size_t qrow = (size_t)(b * LSEQ + qbase + fc * 16 + lr) * LDQKV + h * HDIM;
        #pragma unroll
        for (int ks = 0; ks < 4; ks++)
            qf[fc][ks] = *(const short8*)(Qp + qrow + ks * 32 + lg * 8);
    }

    f32x4 oacc[2][8];
    #pragma unroll
    for (int m = 0; m < 2; m++)
        #pragma unroll
        for (int n = 0; n < 8; n++)
            oacc[m][n] = (f32x4){0.f, 0.f, 0.f, 0.f};
    float lpart[2] = {0.f, 0.f};

    const float scale = 0.08838834764831845f;
    unsigned short* Plw = Pl + w * 2048;

    auto stageK = [&](int kt, int buf) {
        #pragma unroll
        for (int it = 0; it < 4; it++) {
            const int bi = it * 4 + w;
            const int r  = bi * 4 + lg;
            const int sc = lr ^ (r & 7);
            const char* src = (const char*)Kp +
                (size_t)(b * LSEQ + kt * 64 + r) * (LDQKV * 2) + h * 256 + sc * 16;
            load16_lds(src, (char*)Ks[buf] + bi * 1024);
        }
    };
    const int k0v = (l & 31) * 2;
    const int d0v = w * 32 + (l >> 5) * 16;

    stageK(0, 0);
    short8 vc0, vc1, vc2, vc3, vn0, vn1, vn2, vn3;
    {
        const size_t vrow = (size_t)(b * LSEQ + k0v) * LDQKV + h * HDIM + d0v;
        vc0 = *(const short8*)(Vp + vrow);
        vc1 = *(const short8*)(Vp + vrow + 8);
        vc2 = *(const short8*)(Vp + vrow + LDQKV);
        vc3 = *(const short8*)(Vp + vrow + LDQKV + 8);
    }

    #pragma unroll 2
    for (int kt = 0; kt < 8; ++kt) {
        asm volatile("" ::: "memory");
        __builtin_amdgcn_s_barrier();
        asm volatile("" ::: "memory");

        if (kt < 7) {
            stageK(kt + 1, (kt + 1) & 1);
            const size_t vrow = (size_t)(b * LSEQ + (kt + 1) * 64 + k0v) * LDQKV + h * HDIM + d0v;
            vn0 = *(const short8*)(Vp + vrow);
            vn1 = *(const short8*)(Vp + vrow + 8);
            vn2 = *(const short8*)(Vp + vrow + LDQKV);
            vn3 = *(const short8*)(Vp + vrow + LDQKV + 8);
        }
        asm volatile("" ::: "memory");

        #pragma unroll
        for (int j = 0; j < 16; j++) {
            const int d = d0v + j;
            unsigned short lo = (unsigned short)((j < 8) ? vc0[j] : vc1[j - 8]);
            unsigned short hi = (unsigned short)((j < 8) ? vc2[j] : vc3[j - 8]);
            unsigned int pk = (unsigned)lo | ((unsigned)hi << 16);
            const int addr = d * 128 + ((((k0v >> 3) ^ (d & 7))) << 4) + (k0v & 7) * 2;
            *(unsigned int*)((char*)Vt + addr) = pk;
        }

        if (kt < 7) { asm volatile("s_waitcnt vmcnt(8)" ::: "memory"); }
        else        { asm volatile("s_waitcnt vmcnt(0)" ::: "memory"); }
        asm volatile("s_waitcnt lgkmcnt(0)" ::: "memory");
        __builtin_amdgcn_s_barrier();
        __builtin_amdgcn_sched_barrier(0);

        const unsigned short* Ksb = Ks[kt & 1];

        f32x4 sacc[4][2];
        #pragma unroll
        for (int fm = 0; fm < 4; fm++)
            #pragma unroll
            for (int fc = 0; fc < 2; fc++)
                sacc[fm][fc] = (f32x4){0.f, 0.f, 0.f, 0.f};
        #pragma unroll
        for (int ks = 0; ks < 4; ks++) {
            short8 af[4];
            #pragma unroll
            for (int fm = 0; fm < 4; fm++) {
                const int r2 = fm * 16 + lr;
                af[fm] = *(const short8*)((const char*)Ksb +
                          r2 * 256 + (((ks * 4 + lg) ^ (lr & 7)) << 4));
            }
            #pragma unroll
            for (int fm = 0; fm < 4; fm++)
                #pragma unroll
                for (int fc = 0; fc < 2; fc++)
                    sacc[fm][fc] = __builtin_amdgcn_mfma_f32_16x16x32_bf16(
                        af[fm], qf[fc][ks], sacc[fm][fc], 0, 0, 0);
        }

        #pragma unroll
        for (int fm = 0; fm < 4; fm++) {
            #pragma unroll
            for (int fc = 0; fc < 2; fc++) {
                float p0 = sacc[fm][fc][0] * scale;
                float p1 = sacc[fm][fc][1] * scale;
                float p2 = sacc[fm][fc][2] * scale;
                float p3 = sacc[fm][fc][3] * scale;
                if (qt == 0 && w == 0 && fc == 0 && lr == 0) {
                    const int kb = kt * 64 + fm * 16 + lg * 4;
                    p0 += tbs[kb + 0]; p1 += tbs[kb + 1];
                    p2 += tbs[kb + 2]; p3 += tbs[kb + 3];
                }
                p0 = __expf(p0); p1 = __expf(p1);
                p2 = __expf(p2); p3 = __expf(p3);
                lpart[fc] += (p0 + p1) + (p2 + p3);
                const int rq = fc * 16 + lr;
                const int chunk = fm * 2 + (lg >> 1);
                const int addr = rq * 128 + ((chunk ^ (rq & 7)) << 4) + (lg & 1) * 8;
                unsigned int lo = (unsigned)f2bf(p0) | ((unsigned)f2bf(p1) << 16);
                unsigned int hi = (unsigned)f2bf(p2) | ((unsigned)f2bf(p3) << 16);
                *(uint2*)((char*)Plw + addr) = make_uint2(lo, hi);
            }
        }

        #pragma unroll
        for (int ks2 = 0; ks2 < 2; ks2++) {
            short8 pf[2];
            #pragma unroll
            for (int fm2 = 0; fm2 < 2; fm2++) {
                const int rq2 = fm2 * 16 + lr;
                pf[fm2] = *(const short8*)((const char*)Plw +
                           rq2 * 128 + (((ks2 * 4 + lg) ^ (rq2 & 7)) << 4));
            }
            #pragma unroll
            for (int fn = 0; fn < 8; fn++) {
                const int d = fn * 16 + lr;
                short8 vf = *(const short8*)((const char*)Vt +
                             d * 128 + (((ks2 * 4 + lg) ^ (d & 7)) << 4));
                #pragma unroll
                for (int fm2 = 0; fm2 < 2; fm2++)
                    oacc[fm2][fn] = __builtin_amdgcn_mfma_f32_16x16x32_bf16(
                        pf[fm2], vf, oacc[fm2][fn], 0, 0, 0);
            }
        }

        vc0 = vn0; vc1 = vn1; vc2 = vn2; vc3 = vn3;
    }

    float l0 = lpart[0], l1 = lpart[1];
    l0 += __shfl_xor(l0, 16); l0 += __shfl_xor(l0, 32);
    l1 += __shfl_xor(l1, 16); l1 += __shfl_xor(l1, 32);
    float* lw = (float*)Plw;
    if (lg == 0) { lw[lr] = l0; lw[16 + lr] = l1; }
    if (h == 0 && lg == 0) {
        lgout[b * LSEQ + qbase + lr]      = l0;
        lgout[b * LSEQ + qbase + 16 + lr] = l1;
    }
    __builtin_amdgcn_s_waitcnt(0);

    #pragma unroll
    for (int fm2 = 0; fm2 < 2; fm2++) {
        float linv[4];
        #pragma unroll
        for (int j = 0; j < 4; j++)
            linv[j] = 1.0f / lw[fm2 * 16 + lg * 4 + j];
        #pragma unroll
        for (int fn = 0; fn < 8; fn++) {
            const int d = fn * 16 + lr;
            #pragma unroll
            for (int j = 0; j < 4; j++) {
                const int q = qbase + fm2 * 16 + lg * 4 + j;
                AOb[(size_t)(b * LSEQ + q) * SDIM + h * HDIM + d] =
                    f2bf(oacc[fm2][fn][j] * linv[j]);
            }
        }
    }
}

// ---------------------------------------------------------------------------
// sw0: recompute h=0 scores, NORMALIZED W0 fp32 (r16 double-buffered).
// ---------------------------------------------------------------------------
__global__ __launch_bounds__(256, 2) void sw0_kernel(
    const unsigned short* __restrict__ QKV,
    const float* __restrict__ tb,
    const float* __restrict__ lsum,
    float* __restrict__ W0)
{
    const int flat = blockIdx.x + 4 * blockIdx.y;
    const int logical = ((flat & 7) << 5) + (flat >> 3);
    const int qt = logical & 3;
    const int b  = logical >> 2;
    const int t  = threadIdx.x;
    const int w  = t >> 6, l = t & 63;
    const int lr = l & 15, lg = l >> 4;
    const int qbase = qt * 128 + w * 32;

    const unsigned short* Qp = QKV;
    const unsigned short* Kp = QKV + 512;

    __shared__ __align__(16) unsigned short Ks[2][8192];
    __shared__ __align__(16) float Sc[4][32][68];

    short8 qf[2][4];
    #pragma unroll
    for (int fc = 0; fc < 2; fc++) {
        const size_t qrow = (size_t)(b * LSEQ + qbase + fc * 16 + lr) * LDQKV;
        #pragma unroll
        for (int ks = 0; ks < 4; ks++)
            qf[fc][ks] = *(const short8*)(Qp + qrow + ks * 32 + lg * 8);
    }

    float linv[2];
    linv[0] = 1.0f / lsum[b * LSEQ + qbase + lr];
    linv[1] = 1.0f / lsum[b * LSEQ + qbase + 16 + lr];

    const float scale = 0.08838834764831845f;

    auto stageK = [&](int kt, int buf) {
        #pragma unroll
        for (int it = 0; it < 4; it++) {
            const int bi = it * 4 + w;
            const int r  = bi * 4 + lg;
            const int sc = lr ^ (r & 7);
            const char* src = (const char*)Kp +
                (size_t)(b * LSEQ + kt * 64 + r) * (LDQKV * 2) + sc * 16;
            load16_lds(src, (char*)Ks[buf] + bi * 1024);
        }
    };

    stageK(0, 0);

    for (int kt = 0; kt < 8; ++kt) {
        asm volatile("" ::: "memory");
        __builtin_amdgcn_s_barrier();
        asm volatile("" ::: "memory");

        if (kt < 7) stageK(kt + 1, (kt + 1) & 1);

        if (kt < 7) { asm volatile("s_waitcnt vmcnt(4)" ::: "memory"); }
        else        { asm volatile("s_waitcnt vmcnt(0)" ::: "memory"); }
        __builtin_amdgcn_s_barrier();
        __builtin_amdgcn_sched_barrier(0);

        const unsigned short* Ksb = Ks[kt & 1];

        f32x4 sacc[4][2];
        #pragma unroll
        for (int fm = 0; fm < 4; fm++)
            #pragma unroll
            for (int fc = 0; fc < 2; fc++)
                sacc[fm][fc] = (f32x4){0.f, 0.f, 0.f, 0.f};
        #pragma unroll
        for (int ks = 0; ks < 4; ks++) {
            short8 af[4];
            #pragma unroll
            for (int fm = 0; fm < 4; fm++) {
                const int r2 = fm * 16 + lr;
                af[fm] = *(const short8*)((const char*)Ksb +
                          r2 * 256 + (((ks * 4 + lg) ^ (lr & 7)) << 4));
            }
            #pragma unroll
            for (int fm = 0; fm < 4; fm++)
                #pragma unroll
                for (int fc = 0; fc < 2; fc++)
                    sacc[fm][fc] = __builtin_amdgcn_mfma_f32_16x16x32_bf16(
                        af[fm], qf[fc][ks], sacc[fm][fc], 0, 0, 0);
        }

        #pragma unroll
        for (int fm = 0; fm < 4; fm++) {
            #pragma unroll
            for (int fc = 0; fc < 2; fc++) {
                float p0 = sacc[fm][fc][0] * scale;
                float p1 = sacc[fm][fc][1] * scale;
                float p2 = sacc[fm][fc][2] * scale;
                float p3 = sacc[fm][fc][3] * scale;
                if (qt == 0 && w == 0 && fc == 0 && lr == 0) {
                    const int kb = kt * 64 + fm * 16 + lg * 4;
                    p0 += tb[kb + 0]; p1 += tb[kb + 1];
                    p2 += tb[kb + 2]; p3 += tb[kb + 3];
                }
                p0 = __expf(p0) * linv[fc]; p1 = __expf(p1) * linv[fc];
                p2 = __expf(p2) * linv[fc]; p3 = __expf(p3) * linv[fc];
                *(float4*)&Sc[w][fc * 16 + lr][fm * 16 + lg * 4] =
                    make_float4(p0, p1, p2, p3);
            }
        }

        #pragma unroll
        for (int i = 0; i < 8; i++) {
            const int row = i * 4 + lg;
            float4 v = *(const float4*)&Sc[w][row][lr * 4];
            *(float4*)(W0 + (size_t)(b * LSEQ + qbase + row) * LSEQ +
                       kt * 64 + lr * 4) = v;
        }
    }
}

// ---------------------------------------------------------------------------
extern "C" void kernel_launch(void* const* d_in, const int* in_sizes, int n_in,
                              void* d_out, int out_size, void* d_ws, size_t ws_size,
                              hipStream_t stream)
{
    const float* s   = (const float*)d_in[0];
    const float* z   = (const float*)d_in[1];
    const float* wq  = (const float*)d_in[2];
    const float* bq  = (const float*)d_in[3];
    const float* wk  = (const float*)d_in[4];
    const float* bk  = (const float*)d_in[5];
    const float* wv  = (const float*)d_in[6];
    const float* bv  = (const float*)d_in[7];
    const float* wo  = (const float*)d_in[8];
    const float* bo  = (const float*)d_in[9];
    const float* wp  = (const float*)d_in[10];
    const float* bp  = (const float*)d_in[11];
    const float* pos = (const float*)d_in[12];
    const float* ew  = (const float*)d_in[13];
    const float* lng = (const float*)d_in[14];
    const float* lnb = (const float*)d_in[15];
    const float* w1  = (const float*)d_in[16];
    const float* b1  = (const float*)d_in[17];
    const float* w2  = (const float*)d_in[18];
    const float* b2  = (const float*)d_in[19];

    float* out = (float*)d_out;
    const size_t oz  = (size_t)NROWS * SDIM;
    const size_t ow  = oz + (size_t)NROWS * 64;
    const size_t ope = ow + (size_t)NROWS * LSEQ;
    const size_t opr = ope + (size_t)NROWS;

    // workspace layout (bytes)
    char* wsb = (char*)d_ws;
    unsigned short* QKV = (unsigned short*)(wsb);
    unsigned short* F   = (unsigned short*)(wsb);
    unsigned short* Xb  = (unsigned short*)(wsb + 100663296);
    unsigned short* s2b = (unsigned short*)(wsb + 134217728);
    unsigned short* hb  = (unsigned short*)(wsb + 167772160);
    unsigned short* wqkvt = (unsigned short*)(wsb + 234881024);
    unsigned short* wot = wqkvt + 786432;
    unsigned short* w1t = wqkvt + 1048576;    // [2048][512]
    unsigned short* w2t = wqkvt + 2097152;    // [512][2048]
    unsigned short* wpT = wqkvt + 3145728;    // [32][512]
    float* bqkv = (float*)(wsb + 234881024 + 6324224);
    float* tb   = bqkv + 1536;
    float* lgv  = tb + 512;

    // 0. weight prep
    wtrans<<<dim3(16, 16), 256, 0, stream>>>(wq, wqkvt, 512, 512);
    wtrans<<<dim3(16, 16), 256, 0, stream>>>(wk, wqkvt + 262144, 512, 512);
    wtrans<<<dim3(16, 16), 256, 0, stream>>>(wv, wqkvt + 524288, 512, 512);
    wtrans<<<dim3(16, 16), 256, 0, stream>>>(wo, wot, 512, 512);
    wtrans<<<dim3(64, 16), 256, 0, stream>>>(w1, w1t, 512, 2048);
    wtrans<<<dim3(16, 64), 256, 0, stream>>>(w2, w2t, 2048, 512);
    wptrans<<<64, 256, 0, stream>>>(wp, wpT);
    bpack<<<1, 512, 0, stream>>>(bq, bk, bv, bqkv);

    // 1. LN(s) -> bf16 Xb (wave-per-row)
    ln_kernel<0, false><<<NROWS / 4, 256, 0, stream>>>(s, Xb, nullptr, nullptr);

    // 1b. profile softmax + entropy (MFMA)
    profile_kernel<<<256, 256, 0, stream>>>(Xb, wpT, bp, out + opr, out + ope);

    // 2. total bias from batch-0 entropy
    bias_kernel<<<1, 512, 0, stream>>>(out + ope, ew, pos, tb);

    // 3. fused QKV projection -> QKV bf16 [32768][1536]
    mgemm7<1, true, false, 0><<<dim3(6, 128), 512, 0, stream>>>(
        Xb, 512, wqkvt, 512, QKV, LDQKV, bqkv, nullptr, 0, 512);

    // 4. MFMA attention -> attn_out bf16 (Xb) + rowsums
    attn_mfma<<<dim3(4, NHEAD, BATCH), 256, 0, stream>>>(
        QKV, tb, Xb, lgv);

    // 4b. head-0 normalized attention weights (fp32)
    sw0_kernel<<<dim3(4, BATCH), 256, 0, stream>>>(QKV, tb, lgv, out + ow);

    // 5. s2 = s + attn_out @ wo + bo  -> bf16 s2b
    mgemm7<1, true, false, 1><<<dim3(2, 128), 512, 0, stream>>>(
        Xb, 512, wot, 512, s2b, 512, bo, s, 512, 512);

    // 6. h = LN(s2)*g + b -> bf16 (bf16 input)
    ln_kernel<1, true><<<NROWS / 4, 256, 0, stream>>>(s2b, hb, lng, lnb);

    // 7. FFN1: F = relu(h @ w1 + b1), bf16 [32768][2048]
    mgemm7<1, true, true, 0><<<dim3(8, 128), 512, 0, stream>>>(
        hb, 512, w1t, 512, F, 2048, b1, nullptr, 0, 512);

    // 8. FFN2: out0 = F @ w2 + b2 + s2b
    mgemm7<0, true, false, 2><<<dim3(2, 128), 512, 0, stream>>>(
        F, 2048, w2t, 2048, out, 512, b2, s2b, 512, 2048);

    // 9. z passthrough
    hipMemcpyAsync(out + oz, z, (size_t)NROWS * 64 * sizeof(float),
                   hipMemcpyDeviceToDevice, stream);
}

// Round 19
// 406.205 us; speedup vs baseline: 1.0412x; 1.0407x over previous
//
#include <hip/hip_runtime.h>
#include <hip/hip_bf16.h>
#include <math.h>

// Problem constants
#define SDIM 512
#define BATCH 64
#define LSEQ 512
#define NHEAD 4
#define HDIM 128
#define NAA 20
#define NROWS (BATCH * LSEQ)   // 32768
#define LDQKV 1536

typedef __attribute__((ext_vector_type(8))) short short8;
typedef __attribute__((ext_vector_type(4))) float f32x4;

__device__ __forceinline__ unsigned short f2bf(float f) {
    unsigned int x = __float_as_uint(f);
    unsigned int r = (x + 0x7fffu + ((x >> 16) & 1u)) >> 16;  // RNE
    return (unsigned short)r;
}
__device__ __forceinline__ float bf2f(unsigned short u) {
    return __uint_as_float((unsigned int)u << 16);
}

__device__ __forceinline__ void load16_lds(const void* g, void* lds) {
    __builtin_amdgcn_global_load_lds(
        (const __attribute__((address_space(1))) unsigned int*)g,
        (__attribute__((address_space(3))) unsigned int*)lds, 16, 0, 0);
}

// ---------------------------------------------------------------------------
// Fused prep kernel: all weight transposes + wpT + bias pack + z passthrough
// in ONE dispatch (replaces 9 small dispatches). Branch is block-uniform.
// ---------------------------------------------------------------------------
__device__ __forceinline__ void wtrans_dev(
    float (*tile)[33], const float* __restrict__ W,
    unsigned short* __restrict__ Wt, int K, int N, int bx, int by, int t)
{
    const int tx = t & 31, ty = t >> 5;
    const int n0 = bx * 32, k0 = by * 32;
    #pragma unroll
    for (int p = 0; p < 4; p++)
        tile[ty + p * 8][tx] = W[(size_t)(k0 + ty + p * 8) * N + n0 + tx];
    __syncthreads();
    #pragma unroll
    for (int p = 0; p < 4; p++)
        Wt[(size_t)(n0 + ty + p * 8) * K + k0 + tx] = f2bf(tile[tx][ty + p * 8]);
}

__global__ __launch_bounds__(256) void prep_kernel(
    const float* __restrict__ wq, const float* __restrict__ wk,
    const float* __restrict__ wv, const float* __restrict__ wo,
    const float* __restrict__ w1, const float* __restrict__ w2,
    const float* __restrict__ wp,
    const float* __restrict__ bq, const float* __restrict__ bk,
    const float* __restrict__ bv,
    const float* __restrict__ z,
    unsigned short* __restrict__ wqkvt, unsigned short* __restrict__ wot,
    unsigned short* __restrict__ w1t, unsigned short* __restrict__ w2t,
    unsigned short* __restrict__ wpT,
    float* __restrict__ bqkv, float* __restrict__ zout)
{
    __shared__ float tile[32][33];
    const int id = blockIdx.x;
    const int t  = threadIdx.x;

    if (id < 256)  { wtrans_dev(tile, wq, wqkvt,          512,  512, id & 15,        id >> 4,        t); return; }
    if (id < 512)  { const int i = id - 256;  wtrans_dev(tile, wk, wqkvt + 262144, 512,  512, i & 15, i >> 4, t); return; }
    if (id < 768)  { const int i = id - 512;  wtrans_dev(tile, wv, wqkvt + 524288, 512,  512, i & 15, i >> 4, t); return; }
    if (id < 1024) { const int i = id - 768;  wtrans_dev(tile, wo, wot,            512,  512, i & 15, i >> 4, t); return; }
    if (id < 2048) { const int i = id - 1024; wtrans_dev(tile, w1, w1t,            512, 2048, i & 63, i >> 6, t); return; }
    if (id < 3072) { const int i = id - 2048; wtrans_dev(tile, w2, w2t,           2048,  512, i & 15, i >> 4, t); return; }
    if (id < 3136) {   // wpT: [32][512] bf16, rows 20..31 zero
        const int g = (id - 3072) * 256 + t;
        const int k = g & 511, j = g >> 9;
        float v = (j < NAA) ? wp[(size_t)k * NAA + j] : 0.0f;
        wpT[(size_t)j * 512 + k] = f2bf(v);
        return;
    }
    if (id == 3136) {  // bias pack (512 entries each, 256 threads)
        bqkv[t]        = bq[t];       bqkv[t + 256]  = bq[t + 256];
        bqkv[512 + t]  = bk[t];       bqkv[768 + t]  = bk[t + 256];
        bqkv[1024 + t] = bv[t];       bqkv[1280 + t] = bv[t + 256];
        return;
    }
    // z passthrough: 2048 blocks x 256 threads x 1 float4 = 8 MB
    const size_t i = (size_t)(id - 3137) * 256 + t;
    ((float4*)zout)[i] = ((const float4*)z)[i];
}

// ---------------------------------------------------------------------------
// LayerNorm: one WAVE per row, no LDS/barriers. INMODE 0=fp32 in, 1=bf16 in.
// ---------------------------------------------------------------------------
template<int INMODE, bool AFFINE>
__global__ __launch_bounds__(256) void ln_kernel(
    const void* __restrict__ inp, unsigned short* __restrict__ out,
    const float* __restrict__ gamma, const float* __restrict__ beta)
{
    const int w = threadIdx.x >> 6, l = threadIdx.x & 63;
    const int r = blockIdx.x * 4 + w;

    float x[8];
    if (INMODE == 0) {
        const float* row = (const float*)inp + (size_t)r * SDIM;
        float4 a = *(const float4*)(row + l * 4);
        float4 b = *(const float4*)(row + 256 + l * 4);
        x[0] = a.x; x[1] = a.y; x[2] = a.z; x[3] = a.w;
        x[4] = b.x; x[5] = b.y; x[6] = b.z; x[7] = b.w;
    } else {
        const unsigned short* row = (const unsigned short*)inp + (size_t)r * SDIM;
        uint2 a = *(const uint2*)(row + l * 4);
        uint2 b = *(const uint2*)(row + 256 + l * 4);
        x[0] = bf2f((unsigned short)(a.x & 0xffff)); x[1] = bf2f((unsigned short)(a.x >> 16));
        x[2] = bf2f((unsigned short)(a.y & 0xffff)); x[3] = bf2f((unsigned short)(a.y >> 16));
        x[4] = bf2f((unsigned short)(b.x & 0xffff)); x[5] = bf2f((unsigned short)(b.x >> 16));
        x[6] = bf2f((unsigned short)(b.y & 0xffff)); x[7] = bf2f((unsigned short)(b.y >> 16));
    }

    float sum = 0.f, sq = 0.f;
    #pragma unroll
    for (int i = 0; i < 8; i++) { sum += x[i]; sq += x[i] * x[i]; }
    #pragma unroll
    for (int o = 1; o < 64; o <<= 1) {
        sum += __shfl_xor(sum, o);
        sq  += __shfl_xor(sq, o);
    }
    const float mean = sum * (1.0f / SDIM);
    const float var  = sq * (1.0f / SDIM) - mean * mean;
    const float inv  = rsqrtf(var + 1e-5f);

    float y[8];
    if (AFFINE) {
        float4 g0 = *(const float4*)(gamma + l * 4);
        float4 g1 = *(const float4*)(gamma + 256 + l * 4);
        float4 b0 = *(const float4*)(beta + l * 4);
        float4 b1 = *(const float4*)(beta + 256 + l * 4);
        y[0] = (x[0]-mean)*inv*g0.x + b0.x; y[1] = (x[1]-mean)*inv*g0.y + b0.y;
        y[2] = (x[2]-mean)*inv*g0.z + b0.z; y[3] = (x[3]-mean)*inv*g0.w + b0.w;
        y[4] = (x[4]-mean)*inv*g1.x + b1.x; y[5] = (x[5]-mean)*inv*g1.y + b1.y;
        y[6] = (x[6]-mean)*inv*g1.z + b1.z; y[7] = (x[7]-mean)*inv*g1.w + b1.w;
    } else {
        #pragma unroll
        for (int i = 0; i < 8; i++) y[i] = (x[i] - mean) * inv;
    }

    unsigned short* orow = out + (size_t)r * SDIM;
    uint2 p0, p1;
    p0.x = (unsigned)f2bf(y[0]) | ((unsigned)f2bf(y[1]) << 16);
    p0.y = (unsigned)f2bf(y[2]) | ((unsigned)f2bf(y[3]) << 16);
    p1.x = (unsigned)f2bf(y[4]) | ((unsigned)f2bf(y[5]) << 16);
    p1.y = (unsigned)f2bf(y[6]) | ((unsigned)f2bf(y[7]) << 16);
    *(uint2*)(orow + l * 4)       = p0;
    *(uint2*)(orow + 256 + l * 4) = p1;
}

// ---------------------------------------------------------------------------
// Profile kernel: logits = s_ln(bf16) @ wpT^T + bp, softmax+entropy epilogue.
// ---------------------------------------------------------------------------
__global__ __launch_bounds__(256) void profile_kernel(
    const unsigned short* __restrict__ A,
    const unsigned short* __restrict__ wpT,
    const float* __restrict__ bp,
    float* __restrict__ probs,
    float* __restrict__ pe)
{
    __shared__ __align__(16) unsigned short As[128 * 64];

    const int t = threadIdx.x;
    const int w = t >> 6, l = t & 63;
    const int lr = l & 15, lg = l >> 4;
    const int m0 = blockIdx.x * 128;

    f32x4 sacc[2][2];
    #pragma unroll
    for (int m = 0; m < 2; m++)
        #pragma unroll
        for (int n = 0; n < 2; n++)
            sacc[m][n] = (f32x4){0.f, 0.f, 0.f, 0.f};

    const int srow  = l >> 3;
    const int swz16 = ((l & 7) ^ srow) << 4;
    const char* pA[4];
    unsigned ldsoff[4];
    #pragma unroll
    for (int i = 0; i < 4; i++) {
        const int row = (w * 4 + i) * 8 + srow;
        pA[i] = (const char*)A + (size_t)(m0 + row) * 1024 + swz16;
        ldsoff[i] = (unsigned)(w * 4 + i) * 1024;
    }

    const int rsw   = (lr & 7) << 4;
    const int foff0 = (lg * 16) ^ rsw;
    const int foff1 = (64 + lg * 16) ^ rsw;
    int arow[2];
    #pragma unroll
    for (int m = 0; m < 2; m++) arow[m] = (w * 32 + m * 16 + lr) * 128;

    for (int k0 = 0; k0 < 512; k0 += 64) {
        const size_t kb = (size_t)k0 * 2;
        #pragma unroll
        for (int i = 0; i < 4; i++)
            load16_lds(pA[i] + kb, (char*)As + ldsoff[i]);
        __syncthreads();

        short8 af[2], bf[2];
        #pragma unroll
        for (int m = 0; m < 2; m++) af[m] = *(const short8*)((const char*)As + arow[m] + foff0);
        #pragma unroll
        for (int n = 0; n < 2; n++)
            bf[n] = *(const short8*)(wpT + (size_t)(n * 16 + lr) * 512 + k0 + lg * 8);
        #pragma unroll
        for (int m = 0; m < 2; m++)
            #pragma unroll
            for (int n = 0; n < 2; n++)
                sacc[m][n] = __builtin_amdgcn_mfma_f32_16x16x32_bf16(af[m], bf[n], sacc[m][n], 0, 0, 0);

        #pragma unroll
        for (int m = 0; m < 2; m++) af[m] = *(const short8*)((const char*)As + arow[m] + foff1);
        #pragma unroll
        for (int n = 0; n < 2; n++)
            bf[n] = *(const short8*)(wpT + (size_t)(n * 16 + lr) * 512 + k0 + 32 + lg * 8);
        #pragma unroll
        for (int m = 0; m < 2; m++)
            #pragma unroll
            for (int n = 0; n < 2; n++)
                sacc[m][n] = __builtin_amdgcn_mfma_f32_16x16x32_bf16(af[m], bf[n], sacc[m][n], 0, 0, 0);

        __syncthreads();
    }

    const float b0 = bp[lr];
    const float b1 = (lr < 4) ? bp[16 + lr] : 0.0f;
    #pragma unroll
    for (int m = 0; m < 2; m++) {
        #pragma unroll
        for (int j = 0; j < 4; j++) {
            const float v0 = sacc[m][0][j] + b0;
            const float e0 = __expf(v0);
            const float v1 = sacc[m][1][j] + b1;
            const float e1 = (lr < 4) ? __expf(v1) : 0.0f;
            float Sp = e0 + e1;
            float Tp = e0 * v0 + ((lr < 4) ? e1 * v1 : 0.0f);
            #pragma unroll
            for (int o = 1; o < 16; o <<= 1) {
                Sp += __shfl_xor(Sp, o);
                Tp += __shfl_xor(Tp, o);
            }
            const float inv = 1.0f / Sp;
            const int row = m0 + w * 32 + m * 16 + lg * 4 + j;
            probs[(size_t)row * NAA + lr] = e0 * inv;
            if (lr < 4) probs[(size_t)row * NAA + 16 + lr] = e1 * inv;
            if (lr == 0) pe[row] = logf(Sp) - Tp * inv;
        }
    }
}

// total_bias[m] = -pe[0,m]*ew + pos_bias[m]
__global__ void bias_kernel(const float* __restrict__ pe,
                            const float* __restrict__ ew,
                            const float* __restrict__ pos,
                            float* __restrict__ tb)
{
    int t = threadIdx.x;  // 512 threads
    tb[t] = -pe[t] * ew[0] + pos[t];
}

// ---------------------------------------------------------------------------
// bf16 MFMA GEMM, 256x256, BK=64, 8-phase pipeline + fragment caching
// (unchanged from r18 best).
// ---------------------------------------------------------------------------
template<int OMODE, bool BIAS, bool RELU, int RESID>
__global__ __launch_bounds__(512, 2) void mgemm7(
    const unsigned short* __restrict__ A, int lda,
    const unsigned short* __restrict__ Bt, int ldb,
    void* __restrict__ Cv, int ldc,
    const float* __restrict__ bias,
    const void* __restrict__ R, int ldr,
    int K)
{
    __shared__ __align__(16) char lds[131072];

    const int t = threadIdx.x;
    const int w = t >> 6, l = t & 63;
    const int wr = w >> 2, wc = w & 3;
    const int lg = l >> 4, lr = l & 15;

    const int gx   = gridDim.x;
    const int nwg  = gx * gridDim.y;
    const int flat = blockIdx.x + gx * blockIdx.y;
    const int cpx  = nwg >> 3;
    const int logical = (flat & 7) * cpx + (flat >> 3);
    const int m0 = (logical / gx) * 256, n0 = (logical % gx) * 256;

    f32x4 acc[8][4];
    #pragma unroll
    for (int m = 0; m < 8; m++)
        #pragma unroll
        for (int n = 0; n < 4; n++)
            acc[m][n] = (f32x4){0.f, 0.f, 0.f, 0.f};

    const int srow = t >> 3;
    const int sch  = (t & 7) ^ (srow & 7);

    auto stageA = [&](int kt, int d, int h) {
        const char* src = (const char*)A +
            ((size_t)(m0 + h * 128 + srow) * lda + sch * 8) * 2 + (size_t)kt * 128;
        char* dst = lds + d * 65536 + h * 16384 + t * 16;
        load16_lds(src, dst);
        load16_lds(src + (size_t)64 * lda * 2, dst + 8192);
    };
    auto stageB = [&](int kt, int d, int h) {
        const char* src = (const char*)Bt +
            ((size_t)(n0 + h * 128 + srow) * ldb + sch * 8) * 2 + (size_t)kt * 128;
        char* dst = lds + d * 65536 + 32768 + h * 16384 + t * 16;
        load16_lds(src, dst);
        load16_lds(src + (size_t)64 * ldb * 2, dst + 8192);
    };

    int aoff[4], boff[2], sw[2];
    #pragma unroll
    for (int mi = 0; mi < 4; mi++) aoff[mi] = (mi * 32 + wr * 16 + lr) * 128;
    #pragma unroll
    for (int ni = 0; ni < 2; ni++) boff[ni] = (ni * 64 + wc * 16 + lr) * 128;
    #pragma unroll
    for (int ks = 0; ks < 2; ks++) sw[ks] = ((ks * 4 + lg) ^ (lr & 7)) << 4;

    short8 afc[2][4];
    short8 bfc0[2][2];
    short8 bfc1[2][2];

    const int NI = K >> 7;

#define MPHASE(D, MH, NH, LOADA, LOADB, BAR, STAGE_STMT, WAIT_STMT) do {       \
    const char* Abase_ = lds + (D) * 65536 + (MH) * 16384;                     \
    const char* Bbase_ = lds + (D) * 65536 + 32768 + (NH) * 16384;             \
    if (LOADA) {                                                               \
        _Pragma("unroll")                                                      \
        for (int ks_ = 0; ks_ < 2; ks_++)                                      \
            _Pragma("unroll")                                                  \
            for (int mi_ = 0; mi_ < 4; mi_++)                                  \
                afc[ks_][mi_] = *(const short8*)(Abase_ + aoff[mi_] + sw[ks_]);\
    }                                                                          \
    short8 (&bf_)[2][2] = (NH) ? bfc1 : bfc0;                                  \
    if (LOADB) {                                                               \
        _Pragma("unroll")                                                      \
        for (int ks_ = 0; ks_ < 2; ks_++)                                      \
            _Pragma("unroll")                                                  \
            for (int ni_ = 0; ni_ < 2; ni_++)                                  \
                bf_[ks_][ni_] = *(const short8*)(Bbase_ + boff[ni_] + sw[ks_]);\
    }                                                                          \
    STAGE_STMT;                                                                \
    WAIT_STMT;                                                                 \
    if (BAR) {                                                                 \
        __builtin_amdgcn_s_barrier();                                          \
        asm volatile("s_waitcnt lgkmcnt(0)" ::: "memory");                     \
        __builtin_amdgcn_sched_barrier(0);                                     \
    }                                                                          \
    __builtin_amdgcn_s_setprio(1);                                             \
    _Pragma("unroll")                                                          \
    for (int ks_ = 0; ks_ < 2; ks_++)                                          \
        _Pragma("unroll")                                                      \
        for (int mi_ = 0; mi_ < 4; mi_++)                                      \
            _Pragma("unroll")                                                  \
            for (int ni_ = 0; ni_ < 2; ni_++)                                  \
                acc[(MH) * 4 + mi_][(NH) * 2 + ni_] =                          \
                    __builtin_amdgcn_mfma_f32_16x16x32_bf16(                   \
                        afc[ks_][mi_], bf_[ks_][ni_],                          \
                        acc[(MH) * 4 + mi_][(NH) * 2 + ni_], 0, 0, 0);         \
    __builtin_amdgcn_s_setprio(0);                                             \
    asm volatile("" ::: "memory");                                             \
} while (0)

    stageA(0, 0, 0); stageB(0, 0, 0); stageB(0, 0, 1); stageA(0, 0, 1);
    stageA(1, 1, 0); stageB(1, 1, 0);
    asm volatile("s_waitcnt vmcnt(4)" ::: "memory");
    __builtin_amdgcn_s_barrier();
    asm volatile("" ::: "memory");

    for (int it = 0; it < NI; ++it) {
        const bool more = (it + 1 < NI);
        const int T1 = 2 * it + 1, T2 = 2 * it + 2, T3 = 2 * it + 3;

        MPHASE(0, 0, 0, 1, 1, 1, { stageB(T1, 1, 1); }, {});
        MPHASE(0, 0, 1, 0, 1, 1, { stageA(T1, 1, 1); }, {});
        MPHASE(0, 1, 0, 1, 0, 1, { if (more) stageA(T2, 0, 0); }, {});
        MPHASE(0, 1, 1, 0, 0, 0, { if (more) stageB(T2, 0, 0); },
               { if (more) { asm volatile("s_waitcnt vmcnt(4)" ::: "memory"); }
                 else      { asm volatile("s_waitcnt vmcnt(0)" ::: "memory"); } });
        MPHASE(1, 0, 0, 1, 1, 1, { if (more) stageA(T2, 0, 1); }, {});
        MPHASE(1, 0, 1, 0, 1, 1, { if (more) stageB(T2, 0, 1); }, {});
        MPHASE(1, 1, 0, 1, 0, 1, { if (more) stageA(T3, 1, 0); }, {});
        MPHASE(1, 1, 1, 0, 0, 0, { if (more) stageB(T3, 1, 0); },
               { if (more) { asm volatile("s_waitcnt vmcnt(4)" ::: "memory"); } });
    }
#undef MPHASE

    __syncthreads();   // all MFMA LDS reads done before epilogue reuses lds

    if (OMODE == 1) {
        unsigned short* cs = (unsigned short*)lds;
        #pragma unroll
        for (int nf = 0; nf < 4; nf++) {
            const int lcol = (nf >> 1) * 128 + (nf & 1) * 64 + wc * 16 + lr;
            const int col = n0 + lcol;
            const float bv = BIAS ? bias[col] : 0.0f;
            #pragma unroll
            for (int mf = 0; mf < 8; mf++) {
                const int lrow0 = (mf >> 2) * 128 + (mf & 3) * 32 + wr * 16 + lg * 4;
                #pragma unroll
                for (int j = 0; j < 4; j++) {
                    float v = acc[mf][nf][j] + bv;
                    if (RELU) v = fmaxf(v, 0.f);
                    const size_t grow = (size_t)(m0 + lrow0 + j);
                    if (RESID == 1) v += ((const float*)R)[grow * ldr + col];
                    if (RESID == 2) v += bf2f(((const unsigned short*)R)[grow * ldr + col]);
                    cs[(lrow0 + j) * 256 + lcol] = f2bf(v);
                }
            }
        }
        __syncthreads();
        unsigned short* Cp = (unsigned short*)Cv;
        #pragma unroll
        for (int i = 0; i < 16; i++) {
            const int slot = i * 512 + t;
            const int row = slot >> 5, c16 = slot & 31;
            short8 v = *(const short8*)(cs + row * 256 + c16 * 8);
            *(short8*)(Cp + (size_t)(m0 + row) * ldc + n0 + c16 * 8) = v;
        }
    } else {
        float* cf = (float*)lds;
        #pragma unroll
        for (int h = 0; h < 2; h++) {
            if (h) __syncthreads();
            #pragma unroll
            for (int nf = 0; nf < 4; nf++) {
                const int lcol = (nf >> 1) * 128 + (nf & 1) * 64 + wc * 16 + lr;
                const int col = n0 + lcol;
                const float bv = BIAS ? bias[col] : 0.0f;
                #pragma unroll
                for (int mi = 0; mi < 4; mi++) {
                    const int mf = h * 4 + mi;
                    const int lrow0 = (mf & 3) * 32 + wr * 16 + lg * 4;
                    #pragma unroll
                    for (int j = 0; j < 4; j++) {
                        float v = acc[mf][nf][j] + bv;
                        if (RELU) v = fmaxf(v, 0.f);
                        const size_t grow = (size_t)(m0 + h * 128 + lrow0 + j);
                        if (RESID == 1) v += ((const float*)R)[grow * ldr + col];
                        if (RESID == 2) v += bf2f(((const unsigned short*)R)[grow * ldr + col]);
                        cf[(lrow0 + j) * 256 + lcol] = v;
                    }
                }
            }
            __syncthreads();
            float* Cp = (float*)Cv;
            #pragma unroll
            for (int i = 0; i < 16; i++) {
                const int slot = i * 512 + t;
                const int row = slot >> 6, c4 = slot & 63;
                float4 v = *(const float4*)(cf + row * 256 + c4 * 4);
                *(float4*)(Cp + (size_t)(m0 + h * 128 + row) * ldc + n0 + c4 * 4) = v;
            }
        }
    }
}

// ---------------------------------------------------------------------------
// MFMA attention, pipelined staging (unchanged).
// ---------------------------------------------------------------------------
__global__ __launch_bounds__(256, 2) void attn_mfma(
    const unsigned short* __restrict__ QKV,
    const float* __restrict__ tb,
    unsigned short* __restrict__ AOb,
    float* __restrict__ lgout)
{
    const int flat = blockIdx.x + 4 * (blockIdx.y + 4 * blockIdx.z);
    const int logical = ((flat & 7) << 7) + (flat >> 3);
    const int qt = logical & 3;
    const int h  = (logical >> 2) & 3;
    const int b  = logical >> 4;
    const int t  = threadIdx.x;
    const int w  = t >> 6, l = t & 63;
    const int lr = l & 15, lg = l >> 4;
    const int qbase = qt * 128 + w * 32;

    const unsigned short* Qp = QKV;
    const unsigned short* Kp = QKV + 512;
    const unsigned short* Vp = QKV + 1024;

    __shared__ __align__(16) unsigned short Ks[2][8192];
    __shared__ __align__(16) unsigned short Vt[8192];
    __shared__ __align__(16) unsigned short Pl[8192];
    __shared__ float tbs[512];

    tbs[t] = tb[t];
    tbs[t + 256] = tb[t + 256];

    short8 qf[2][4];
    #pragma unroll
    for (int fc = 0; fc < 2; fc++) {
        const size_t qrow = (size_t)(b * LSEQ + qbase + fc * 16 + lr) * LDQKV + h * HDIM;
        #pragma unroll
        for (int ks = 0; ks < 4; ks++)
            qf[fc][ks] = *(const short8*)(Qp + qrow + ks * 32 + lg * 8);
    }

    f32x4 oacc[2][8];
    #pragma unroll
    for (int m = 0; m < 2; m++)
        #pragma unroll
        for (int n = 0; n < 8; n++)
            oacc[m][n] = (f32x4){0.f, 0.f, 0.f, 0.f};
    float lpart[2] = {0.f, 0.f};

    const float scale = 0.08838834764831845f;
    unsigned short* Plw = Pl + w * 2048;

    auto stageK = [&](int kt, int buf) {
        #pragma unroll
        for (int it = 0; it < 4; it++) {
            const int bi = it * 4 + w;
            const int r  = bi * 4 + lg;
            const int sc = lr ^ (r & 7);
            const char* src = (const char*)Kp +
                (size_t)(b * LSEQ + kt * 64 + r) * (LDQKV * 2) + h * 256 + sc * 16;
            load16_lds(src, (char*)Ks[buf] + bi * 1024);
        }
    };
    const int k0v = (l & 31) * 2;
    const int d0v = w * 32 + (l >> 5) * 16;

    stageK(0, 0);
    short8 vc0, vc1, vc2, vc3, vn0, vn1, vn2, vn3;
    {
        const size_t vrow = (size_t)(b * LSEQ + k0v) * LDQKV + h * HDIM + d0v;
        vc0 = *(const short8*)(Vp + vrow);
        vc1 = *(const short8*)(Vp + vrow + 8);
        vc2 = *(const short8*)(Vp + vrow + LDQKV);
        vc3 = *(const short8*)(Vp + vrow + LDQKV + 8);
    }

    #pragma unroll 2
    for (int kt = 0; kt < 8; ++kt) {
        asm volatile("" ::: "memory");
        __builtin_amdgcn_s_barrier();
        asm volatile("" ::: "memory");

        if (kt < 7) {
            stageK(kt + 1, (kt + 1) & 1);
            const size_t vrow = (size_t)(b * LSEQ + (kt + 1) * 64 + k0v) * LDQKV + h * HDIM + d0v;
            vn0 = *(const short8*)(Vp + vrow);
            vn1 = *(const short8*)(Vp + vrow + 8);
            vn2 = *(const short8*)(Vp + vrow + LDQKV);
            vn3 = *(const short8*)(Vp + vrow + LDQKV + 8);
        }
        asm volatile("" ::: "memory");

        #pragma unroll
        for (int j = 0; j < 16; j++) {
            const int d = d0v + j;
            unsigned short lo = (unsigned short)((j < 8) ? vc0[j] : vc1[j - 8]);
            unsigned short hi = (unsigned short)((j < 8) ? vc2[j] : vc3[j - 8]);
            unsigned int pk = (unsigned)lo | ((unsigned)hi << 16);
            const int addr = d * 128 + ((((k0v >> 3) ^ (d & 7))) << 4) + (k0v & 7) * 2;
            *(unsigned int*)((char*)Vt + addr) = pk;
        }

        if (kt < 7) { asm volatile("s_waitcnt vmcnt(8)" ::: "memory"); }
        else        { asm volatile("s_waitcnt vmcnt(0)" ::: "memory"); }
        asm volatile("s_waitcnt lgkmcnt(0)" ::: "memory");
        __builtin_amdgcn_s_barrier();
        __builtin_amdgcn_sched_barrier(0);

        const unsigned short* Ksb = Ks[kt & 1];

        f32x4 sacc[4][2];
        #pragma unroll
        for (int fm = 0; fm < 4; fm++)
            #pragma unroll
            for (int fc = 0; fc < 2; fc++)
                sacc[fm][fc] = (f32x4){0.f, 0.f, 0.f, 0.f};
        #pragma unroll
        for (int ks = 0; ks < 4; ks++) {
            short8 af[4];
            #pragma unroll
            for (int fm = 0; fm < 4; fm++) {
                const int r2 = fm * 16 + lr;
                af[fm] = *(const short8*)((const char*)Ksb +
                          r2 * 256 + (((ks * 4 + lg) ^ (lr & 7)) << 4));
            }
            #pragma unroll
            for (int fm = 0; fm < 4; fm++)
                #pragma unroll
                for (int fc = 0; fc < 2; fc++)
                    sacc[fm][fc] = __builtin_amdgcn_mfma_f32_16x16x32_bf16(
                        af[fm], qf[fc][ks], sacc[fm][fc], 0, 0, 0);
        }

        #pragma unroll
        for (int fm = 0; fm < 4; fm++) {
            #pragma unroll
            for (int fc = 0; fc < 2; fc++) {
                float p0 = sacc[fm][fc][0] * scale;
                float p1 = sacc[fm][fc][1] * scale;
                float p2 = sacc[fm][fc][2] * scale;
                float p3 = sacc[fm][fc][3] * scale;
                if (qt == 0 && w == 0 && fc == 0 && lr == 0) {
                    const int kb = kt * 64 + fm * 16 + lg * 4;
                    p0 += tbs[kb + 0]; p1 += tbs[kb + 1];
                    p2 += tbs[kb + 2]; p3 += tbs[kb + 3];
                }
                p0 = __expf(p0); p1 = __expf(p1);
                p2 = __expf(p2); p3 = __expf(p3);
                lpart[fc] += (p0 + p1) + (p2 + p3);
                const int rq = fc * 16 + lr;
                const int chunk = fm * 2 + (lg >> 1);
                const int addr = rq * 128 + ((chunk ^ (rq & 7)) << 4) + (lg & 1) * 8;
                unsigned int lo = (unsigned)f2bf(p0) | ((unsigned)f2bf(p1) << 16);
                unsigned int hi = (unsigned)f2bf(p2) | ((unsigned)f2bf(p3) << 16);
                *(uint2*)((char*)Plw + addr) = make_uint2(lo, hi);
            }
        }

        #pragma unroll
        for (int ks2 = 0; ks2 < 2; ks2++) {
            short8 pf[2];
            #pragma unroll
            for (int fm2 = 0; fm2 < 2; fm2++) {
                const int rq2 = fm2 * 16 + lr;
                pf[fm2] = *(const short8*)((const char*)Plw +
                           rq2 * 128 + (((ks2 * 4 + lg) ^ (rq2 & 7)) << 4));
            }
            #pragma unroll
            for (int fn = 0; fn < 8; fn++) {
                const int d = fn * 16 + lr;
                short8 vf = *(const short8*)((const char*)Vt +
                             d * 128 + (((ks2 * 4 + lg) ^ (d & 7)) << 4));
                #pragma unroll
                for (int fm2 = 0; fm2 < 2; fm2++)
                    oacc[fm2][fn] = __builtin_amdgcn_mfma_f32_16x16x32_bf16(
                        pf[fm2], vf, oacc[fm2][fn], 0, 0, 0);
            }
        }

        vc0 = vn0; vc1 = vn1; vc2 = vn2; vc3 = vn3;
    }

    float l0 = lpart[0], l1 = lpart[1];
    l0 += __shfl_xor(l0, 16); l0 += __shfl_xor(l0, 32);
    l1 += __shfl_xor(l1, 16); l1 += __shfl_xor(l1, 32);
    float* lw = (float*)Plw;
    if (lg == 0) { lw[lr] = l0; lw[16 + lr] = l1; }
    if (h == 0 && lg == 0) {
        lgout[b * LSEQ + qbase + lr]      = l0;
        lgout[b * LSEQ + qbase + 16 + lr] = l1;
    }
    __builtin_amdgcn_s_waitcnt(0);

    #pragma unroll
    for (int fm2 = 0; fm2 < 2; fm2++) {
        float linv[4];
        #pragma unroll
        for (int j = 0; j < 4; j++)
            linv[j] = 1.0f / lw[fm2 * 16 + lg * 4 + j];
        #pragma unroll
        for (int fn = 0; fn < 8; fn++) {
            const int d = fn * 16 + lr;
            #pragma unroll
            for (int j = 0; j < 4; j++) {
                const int q = qbase + fm2 * 16 + lg * 4 + j;
                AOb[(size_t)(b * LSEQ + q) * SDIM + h * HDIM + d] =
                    f2bf(oacc[fm2][fn][j] * linv[j]);
            }
        }
    }
}

// ---------------------------------------------------------------------------
// sw0: recompute h=0 scores, NORMALIZED W0 fp32 (double-buffered).
// ---------------------------------------------------------------------------
__global__ __launch_bounds__(256, 2) void sw0_kernel(
    const unsigned short* __restrict__ QKV,
    const float* __restrict__ tb,
    const float* __restrict__ lsum,
    float* __restrict__ W0)
{
    const int flat = blockIdx.x + 4 * blockIdx.y;
    const int logical = ((flat & 7) << 5) + (flat >> 3);
    const int qt = logical & 3;
    const int b  = logical >> 2;
    const int t  = threadIdx.x;
    const int w  = t >> 6, l = t & 63;
    const int lr = l & 15, lg = l >> 4;
    const int qbase = qt * 128 + w * 32;

    const unsigned short* Qp = QKV;
    const unsigned short* Kp = QKV + 512;

    __shared__ __align__(16) unsigned short Ks[2][8192];
    __shared__ __align__(16) float Sc[4][32][68];

    short8 qf[2][4];
    #pragma unroll
    for (int fc = 0; fc < 2; fc++) {
        const size_t qrow = (size_t)(b * LSEQ + qbase + fc * 16 + lr) * LDQKV;
        #pragma unroll
        for (int ks = 0; ks < 4; ks++)
            qf[fc][ks] = *(const short8*)(Qp + qrow + ks * 32 + lg * 8);
    }

    float linv[2];
    linv[0] = 1.0f / lsum[b * LSEQ + qbase + lr];
    linv[1] = 1.0f / lsum[b * LSEQ + qbase + 16 + lr];

    const float scale = 0.08838834764831845f;

    auto stageK = [&](int kt, int buf) {
        #pragma unroll
        for (int it = 0; it < 4; it++) {
            const int bi = it * 4 + w;
            const int r  = bi * 4 + lg;
            const int sc = lr ^ (r & 7);
            const char* src = (const char*)Kp +
                (size_t)(b * LSEQ + kt * 64 + r) * (LDQKV * 2) + sc * 16;
            load16_lds(src, (char*)Ks[buf] + bi * 1024);
        }
    };

    stageK(0, 0);

    for (int kt = 0; kt < 8; ++kt) {
        asm volatile("" ::: "memory");
        __builtin_amdgcn_s_barrier();
        asm volatile("" ::: "memory");

        if (kt < 7) stageK(kt + 1, (kt + 1) & 1);

        if (kt < 7) { asm volatile("s_waitcnt vmcnt(4)" ::: "memory"); }
        else        { asm volatile("s_waitcnt vmcnt(0)" ::: "memory"); }
        __builtin_amdgcn_s_barrier();
        __builtin_amdgcn_sched_barrier(0);

        const unsigned short* Ksb = Ks[kt & 1];

        f32x4 sacc[4][2];
        #pragma unroll
        for (int fm = 0; fm < 4; fm++)
            #pragma unroll
            for (int fc = 0; fc < 2; fc++)
                sacc[fm][fc] = (f32x4){0.f, 0.f, 0.f, 0.f};
        #pragma unroll
        for (int ks = 0; ks < 4; ks++) {
            short8 af[4];
            #pragma unroll
            for (int fm = 0; fm < 4; fm++) {
                const int r2 = fm * 16 + lr;
                af[fm] = *(const short8*)((const char*)Ksb +
                          r2 * 256 + (((ks * 4 + lg) ^ (lr & 7)) << 4));
            }
            #pragma unroll
            for (int fm = 0; fm < 4; fm++)
                #pragma unroll
                for (int fc = 0; fc < 2; fc++)
                    sacc[fm][fc] = __builtin_amdgcn_mfma_f32_16x16x32_bf16(
                        af[fm], qf[fc][ks], sacc[fm][fc], 0, 0, 0);
        }

        #pragma unroll
        for (int fm = 0; fm < 4; fm++) {
            #pragma unroll
            for (int fc = 0; fc < 2; fc++) {
                float p0 = sacc[fm][fc][0] * scale;
                float p1 = sacc[fm][fc][1] * scale;
                float p2 = sacc[fm][fc][2] * scale;
                float p3 = sacc[fm][fc][3] * scale;
                if (qt == 0 && w == 0 && fc == 0 && lr == 0) {
                    const int kb = kt * 64 + fm * 16 + lg * 4;
                    p0 += tb[kb + 0]; p1 += tb[kb + 1];
                    p2 += tb[kb + 2]; p3 += tb[kb + 3];
                }
                p0 = __expf(p0) * linv[fc]; p1 = __expf(p1) * linv[fc];
                p2 = __expf(p2) * linv[fc]; p3 = __expf(p3) * linv[fc];
                *(float4*)&Sc[w][fc * 16 + lr][fm * 16 + lg * 4] =
                    make_float4(p0, p1, p2, p3);
            }
        }

        #pragma unroll
        for (int i = 0; i < 8; i++) {
            const int row = i * 4 + lg;
            float4 v = *(const float4*)&Sc[w][row][lr * 4];
            *(float4*)(W0 + (size_t)(b * LSEQ + qbase + row) * LSEQ +
                       kt * 64 + lr * 4) = v;
        }
    }
}

// ---------------------------------------------------------------------------
extern "C" void kernel_launch(void* const* d_in, const int* in_sizes, int n_in,
                              void* d_out, int out_size, void* d_ws, size_t ws_size,
                              hipStream_t stream)
{
    const float* s   = (const float*)d_in[0];
    const float* z   = (const float*)d_in[1];
    const float* wq  = (const float*)d_in[2];
    const float* bq  = (const float*)d_in[3];
    const float* wk  = (const float*)d_in[4];
    const float* bk  = (const float*)d_in[5];
    const float* wv  = (const float*)d_in[6];
    const float* bv  = (const float*)d_in[7];
    const float* wo  = (const float*)d_in[8];
    const float* bo  = (const float*)d_in[9];
    const float* wp  = (const float*)d_in[10];
    const float* bp  = (const float*)d_in[11];
    const float* pos = (const float*)d_in[12];
    const float* ew  = (const float*)d_in[13];
    const float* lng = (const float*)d_in[14];
    const float* lnb = (const float*)d_in[15];
    const float* w1  = (const float*)d_in[16];
    const float* b1  = (const float*)d_in[17];
    const float* w2  = (const float*)d_in[18];
    const float* b2  = (const float*)d_in[19];

    float* out = (float*)d_out;
    const size_t oz  = (size_t)NROWS * SDIM;
    const size_t ow  = oz + (size_t)NROWS * 64;
    const size_t ope = ow + (size_t)NROWS * LSEQ;
    const size_t opr = ope + (size_t)NROWS;

    // workspace layout (bytes)
    char* wsb = (char*)d_ws;
    unsigned short* QKV = (unsigned short*)(wsb);
    unsigned short* F   = (unsigned short*)(wsb);
    unsigned short* Xb  = (unsigned short*)(wsb + 100663296);
    unsigned short* s2b = (unsigned short*)(wsb + 134217728);
    unsigned short* hb  = (unsigned short*)(wsb + 167772160);
    unsigned short* wqkvt = (unsigned short*)(wsb + 234881024);
    unsigned short* wot = wqkvt + 786432;
    unsigned short* w1t = wqkvt + 1048576;    // [2048][512]
    unsigned short* w2t = wqkvt + 2097152;    // [512][2048]
    unsigned short* wpT = wqkvt + 3145728;    // [32][512]
    float* bqkv = (float*)(wsb + 234881024 + 6324224);
    float* tb   = bqkv + 1536;
    float* lgv  = tb + 512;

    // 0. fused prep: all weight transposes + wpT + bias pack + z passthrough
    prep_kernel<<<5185, 256, 0, stream>>>(
        wq, wk, wv, wo, w1, w2, wp, bq, bk, bv, z,
        wqkvt, wot, w1t, w2t, wpT, bqkv, out + oz);

    // 1. LN(s) -> bf16 Xb (wave-per-row)
    ln_kernel<0, false><<<NROWS / 4, 256, 0, stream>>>(s, Xb, nullptr, nullptr);

    // 1b. profile softmax + entropy (MFMA)
    profile_kernel<<<256, 256, 0, stream>>>(Xb, wpT, bp, out + opr, out + ope);

    // 2. total bias from batch-0 entropy
    bias_kernel<<<1, 512, 0, stream>>>(out + ope, ew, pos, tb);

    // 3. fused QKV projection -> QKV bf16 [32768][1536]
    mgemm7<1, true, false, 0><<<dim3(6, 128), 512, 0, stream>>>(
        Xb, 512, wqkvt, 512, QKV, LDQKV, bqkv, nullptr, 0, 512);

    // 4. MFMA attention -> attn_out bf16 (Xb) + rowsums
    attn_mfma<<<dim3(4, NHEAD, BATCH), 256, 0, stream>>>(
        QKV, tb, Xb, lgv);

    // 4b. head-0 normalized attention weights (fp32)
    sw0_kernel<<<dim3(4, BATCH), 256, 0, stream>>>(QKV, tb, lgv, out + ow);

    // 5. s2 = s + attn_out @ wo + bo  -> bf16 s2b
    mgemm7<1, true, false, 1><<<dim3(2, 128), 512, 0, stream>>>(
        Xb, 512, wot, 512, s2b, 512, bo, s, 512, 512);

    // 6. h = LN(s2)*g + b -> bf16 (bf16 input)
    ln_kernel<1, true><<<NROWS / 4, 256, 0, stream>>>(s2b, hb, lng, lnb);

    // 7. FFN1: F = relu(h @ w1 + b1), bf16 [32768][2048]
    mgemm7<1, true, true, 0><<<dim3(8, 128), 512, 0, stream>>>(
        hb, 512, w1t, 512, F, 2048, b1, nullptr, 0, 512);

    // 8. FFN2: out0 = F @ w2 + b2 + s2b
    mgemm7<0, true, false, 2><<<dim3(2, 128), 512, 0, stream>>>(
        F, 2048, w2t, 2048, out, 512, b2, s2b, 512, 2048);
}

// Round 20
// 399.182 us; speedup vs baseline: 1.0595x; 1.0176x over previous
//
#include <hip/hip_runtime.h>
#include <hip/hip_bf16.h>
#include <math.h>

// Problem constants
#define SDIM 512
#define BATCH 64
#define LSEQ 512
#define NHEAD 4
#define HDIM 128
#define NAA 20
#define NROWS (BATCH * LSEQ)   // 32768
#define LDQKV 1536

typedef __attribute__((ext_vector_type(8))) short short8;
typedef __attribute__((ext_vector_type(4))) float f32x4;

__device__ __forceinline__ unsigned short f2bf(float f) {
    unsigned int x = __float_as_uint(f);
    unsigned int r = (x + 0x7fffu + ((x >> 16) & 1u)) >> 16;  // RNE
    return (unsigned short)r;
}
__device__ __forceinline__ float bf2f(unsigned short u) {
    return __uint_as_float((unsigned int)u << 16);
}

__device__ __forceinline__ void load16_lds(const void* g, void* lds) {
    __builtin_amdgcn_global_load_lds(
        (const __attribute__((address_space(1))) unsigned int*)g,
        (__attribute__((address_space(3))) unsigned int*)lds, 16, 0, 0);
}

// ---------------------------------------------------------------------------
// Fused prep kernel: weight transposes + wpT + bias pack + z passthrough +
// LN1 (s -> bf16 Xb), all in ONE dispatch. Branch is block-uniform.
// ---------------------------------------------------------------------------
__device__ __forceinline__ void wtrans_dev(
    float (*tile)[33], const float* __restrict__ W,
    unsigned short* __restrict__ Wt, int K, int N, int bx, int by, int t)
{
    const int tx = t & 31, ty = t >> 5;
    const int n0 = bx * 32, k0 = by * 32;
    #pragma unroll
    for (int p = 0; p < 4; p++)
        tile[ty + p * 8][tx] = W[(size_t)(k0 + ty + p * 8) * N + n0 + tx];
    __syncthreads();
    #pragma unroll
    for (int p = 0; p < 4; p++)
        Wt[(size_t)(n0 + ty + p * 8) * K + k0 + tx] = f2bf(tile[tx][ty + p * 8]);
}

__global__ __launch_bounds__(256) void prep_kernel(
    const float* __restrict__ wq, const float* __restrict__ wk,
    const float* __restrict__ wv, const float* __restrict__ wo,
    const float* __restrict__ w1, const float* __restrict__ w2,
    const float* __restrict__ wp,
    const float* __restrict__ bq, const float* __restrict__ bk,
    const float* __restrict__ bv,
    const float* __restrict__ z,
    const float* __restrict__ s,
    unsigned short* __restrict__ wqkvt, unsigned short* __restrict__ wot,
    unsigned short* __restrict__ w1t, unsigned short* __restrict__ w2t,
    unsigned short* __restrict__ wpT,
    float* __restrict__ bqkv, float* __restrict__ zout,
    unsigned short* __restrict__ Xb)
{
    __shared__ float tile[32][33];
    const int id = blockIdx.x;
    const int t  = threadIdx.x;

    if (id < 256)  { wtrans_dev(tile, wq, wqkvt,          512,  512, id & 15,        id >> 4,        t); return; }
    if (id < 512)  { const int i = id - 256;  wtrans_dev(tile, wk, wqkvt + 262144, 512,  512, i & 15, i >> 4, t); return; }
    if (id < 768)  { const int i = id - 512;  wtrans_dev(tile, wv, wqkvt + 524288, 512,  512, i & 15, i >> 4, t); return; }
    if (id < 1024) { const int i = id - 768;  wtrans_dev(tile, wo, wot,            512,  512, i & 15, i >> 4, t); return; }
    if (id < 2048) { const int i = id - 1024; wtrans_dev(tile, w1, w1t,            512, 2048, i & 63, i >> 6, t); return; }
    if (id < 3072) { const int i = id - 2048; wtrans_dev(tile, w2, w2t,           2048,  512, i & 15, i >> 4, t); return; }
    if (id < 3136) {   // wpT: [32][512] bf16, rows 20..31 zero
        const int g = (id - 3072) * 256 + t;
        const int k = g & 511, j = g >> 9;
        float v = (j < NAA) ? wp[(size_t)k * NAA + j] : 0.0f;
        wpT[(size_t)j * 512 + k] = f2bf(v);
        return;
    }
    if (id == 3136) {  // bias pack
        bqkv[t]        = bq[t];       bqkv[t + 256]  = bq[t + 256];
        bqkv[512 + t]  = bk[t];       bqkv[768 + t]  = bk[t + 256];
        bqkv[1024 + t] = bv[t];       bqkv[1280 + t] = bv[t + 256];
        return;
    }
    if (id < 5185) {   // z passthrough: 2048 blocks x 256 threads x float4
        const size_t i = (size_t)(id - 3137) * 256 + t;
        ((float4*)zout)[i] = ((const float4*)z)[i];
        return;
    }
    // LN1: 8192 blocks, wave-per-row, 4 rows/block (same math as ln_kernel<0,false>)
    {
        const int w = t >> 6, l = t & 63;
        const int r = (id - 5185) * 4 + w;
        const float* row = s + (size_t)r * SDIM;
        float4 a = *(const float4*)(row + l * 4);
        float4 b = *(const float4*)(row + 256 + l * 4);
        float x[8] = {a.x, a.y, a.z, a.w, b.x, b.y, b.z, b.w};

        float sum = 0.f, sq = 0.f;
        #pragma unroll
        for (int i = 0; i < 8; i++) { sum += x[i]; sq += x[i] * x[i]; }
        #pragma unroll
        for (int o = 1; o < 64; o <<= 1) {
            sum += __shfl_xor(sum, o);
            sq  += __shfl_xor(sq, o);
        }
        const float mean = sum * (1.0f / SDIM);
        const float var  = sq * (1.0f / SDIM) - mean * mean;
        const float inv  = rsqrtf(var + 1e-5f);

        float y[8];
        #pragma unroll
        for (int i = 0; i < 8; i++) y[i] = (x[i] - mean) * inv;

        unsigned short* orow = Xb + (size_t)r * SDIM;
        uint2 p0, p1;
        p0.x = (unsigned)f2bf(y[0]) | ((unsigned)f2bf(y[1]) << 16);
        p0.y = (unsigned)f2bf(y[2]) | ((unsigned)f2bf(y[3]) << 16);
        p1.x = (unsigned)f2bf(y[4]) | ((unsigned)f2bf(y[5]) << 16);
        p1.y = (unsigned)f2bf(y[6]) | ((unsigned)f2bf(y[7]) << 16);
        *(uint2*)(orow + l * 4)       = p0;
        *(uint2*)(orow + 256 + l * 4) = p1;
    }
}

// ---------------------------------------------------------------------------
// LayerNorm (LN2 only now): one WAVE per row. INMODE 1 = bf16 in.
// ---------------------------------------------------------------------------
template<int INMODE, bool AFFINE>
__global__ __launch_bounds__(256) void ln_kernel(
    const void* __restrict__ inp, unsigned short* __restrict__ out,
    const float* __restrict__ gamma, const float* __restrict__ beta)
{
    const int w = threadIdx.x >> 6, l = threadIdx.x & 63;
    const int r = blockIdx.x * 4 + w;

    float x[8];
    if (INMODE == 0) {
        const float* row = (const float*)inp + (size_t)r * SDIM;
        float4 a = *(const float4*)(row + l * 4);
        float4 b = *(const float4*)(row + 256 + l * 4);
        x[0] = a.x; x[1] = a.y; x[2] = a.z; x[3] = a.w;
        x[4] = b.x; x[5] = b.y; x[6] = b.z; x[7] = b.w;
    } else {
        const unsigned short* row = (const unsigned short*)inp + (size_t)r * SDIM;
        uint2 a = *(const uint2*)(row + l * 4);
        uint2 b = *(const uint2*)(row + 256 + l * 4);
        x[0] = bf2f((unsigned short)(a.x & 0xffff)); x[1] = bf2f((unsigned short)(a.x >> 16));
        x[2] = bf2f((unsigned short)(a.y & 0xffff)); x[3] = bf2f((unsigned short)(a.y >> 16));
        x[4] = bf2f((unsigned short)(b.x & 0xffff)); x[5] = bf2f((unsigned short)(b.x >> 16));
        x[6] = bf2f((unsigned short)(b.y & 0xffff)); x[7] = bf2f((unsigned short)(b.y >> 16));
    }

    float sum = 0.f, sq = 0.f;
    #pragma unroll
    for (int i = 0; i < 8; i++) { sum += x[i]; sq += x[i] * x[i]; }
    #pragma unroll
    for (int o = 1; o < 64; o <<= 1) {
        sum += __shfl_xor(sum, o);
        sq  += __shfl_xor(sq, o);
    }
    const float mean = sum * (1.0f / SDIM);
    const float var  = sq * (1.0f / SDIM) - mean * mean;
    const float inv  = rsqrtf(var + 1e-5f);

    float y[8];
    if (AFFINE) {
        float4 g0 = *(const float4*)(gamma + l * 4);
        float4 g1 = *(const float4*)(gamma + 256 + l * 4);
        float4 b0 = *(const float4*)(beta + l * 4);
        float4 b1 = *(const float4*)(beta + 256 + l * 4);
        y[0] = (x[0]-mean)*inv*g0.x + b0.x; y[1] = (x[1]-mean)*inv*g0.y + b0.y;
        y[2] = (x[2]-mean)*inv*g0.z + b0.z; y[3] = (x[3]-mean)*inv*g0.w + b0.w;
        y[4] = (x[4]-mean)*inv*g1.x + b1.x; y[5] = (x[5]-mean)*inv*g1.y + b1.y;
        y[6] = (x[6]-mean)*inv*g1.z + b1.z; y[7] = (x[7]-mean)*inv*g1.w + b1.w;
    } else {
        #pragma unroll
        for (int i = 0; i < 8; i++) y[i] = (x[i] - mean) * inv;
    }

    unsigned short* orow = out + (size_t)r * SDIM;
    uint2 p0, p1;
    p0.x = (unsigned)f2bf(y[0]) | ((unsigned)f2bf(y[1]) << 16);
    p0.y = (unsigned)f2bf(y[2]) | ((unsigned)f2bf(y[3]) << 16);
    p1.x = (unsigned)f2bf(y[4]) | ((unsigned)f2bf(y[5]) << 16);
    p1.y = (unsigned)f2bf(y[6]) | ((unsigned)f2bf(y[7]) << 16);
    *(uint2*)(orow + l * 4)       = p0;
    *(uint2*)(orow + 256 + l * 4) = p1;
}

// ---------------------------------------------------------------------------
// Profile kernel: logits = s_ln(bf16) @ wpT^T + bp, softmax+entropy epilogue.
// ---------------------------------------------------------------------------
__global__ __launch_bounds__(256) void profile_kernel(
    const unsigned short* __restrict__ A,
    const unsigned short* __restrict__ wpT,
    const float* __restrict__ bp,
    float* __restrict__ probs,
    float* __restrict__ pe)
{
    __shared__ __align__(16) unsigned short As[128 * 64];

    const int t = threadIdx.x;
    const int w = t >> 6, l = t & 63;
    const int lr = l & 15, lg = l >> 4;
    const int m0 = blockIdx.x * 128;

    f32x4 sacc[2][2];
    #pragma unroll
    for (int m = 0; m < 2; m++)
        #pragma unroll
        for (int n = 0; n < 2; n++)
            sacc[m][n] = (f32x4){0.f, 0.f, 0.f, 0.f};

    const int srow  = l >> 3;
    const int swz16 = ((l & 7) ^ srow) << 4;
    const char* pA[4];
    unsigned ldsoff[4];
    #pragma unroll
    for (int i = 0; i < 4; i++) {
        const int row = (w * 4 + i) * 8 + srow;
        pA[i] = (const char*)A + (size_t)(m0 + row) * 1024 + swz16;
        ldsoff[i] = (unsigned)(w * 4 + i) * 1024;
    }

    const int rsw   = (lr & 7) << 4;
    const int foff0 = (lg * 16) ^ rsw;
    const int foff1 = (64 + lg * 16) ^ rsw;
    int arow[2];
    #pragma unroll
    for (int m = 0; m < 2; m++) arow[m] = (w * 32 + m * 16 + lr) * 128;

    for (int k0 = 0; k0 < 512; k0 += 64) {
        const size_t kb = (size_t)k0 * 2;
        #pragma unroll
        for (int i = 0; i < 4; i++)
            load16_lds(pA[i] + kb, (char*)As + ldsoff[i]);
        __syncthreads();

        short8 af[2], bf[2];
        #pragma unroll
        for (int m = 0; m < 2; m++) af[m] = *(const short8*)((const char*)As + arow[m] + foff0);
        #pragma unroll
        for (int n = 0; n < 2; n++)
            bf[n] = *(const short8*)(wpT + (size_t)(n * 16 + lr) * 512 + k0 + lg * 8);
        #pragma unroll
        for (int m = 0; m < 2; m++)
            #pragma unroll
            for (int n = 0; n < 2; n++)
                sacc[m][n] = __builtin_amdgcn_mfma_f32_16x16x32_bf16(af[m], bf[n], sacc[m][n], 0, 0, 0);

        #pragma unroll
        for (int m = 0; m < 2; m++) af[m] = *(const short8*)((const char*)As + arow[m] + foff1);
        #pragma unroll
        for (int n = 0; n < 2; n++)
            bf[n] = *(const short8*)(wpT + (size_t)(n * 16 + lr) * 512 + k0 + 32 + lg * 8);
        #pragma unroll
        for (int m = 0; m < 2; m++)
            #pragma unroll
            for (int n = 0; n < 2; n++)
                sacc[m][n] = __builtin_amdgcn_mfma_f32_16x16x32_bf16(af[m], bf[n], sacc[m][n], 0, 0, 0);

        __syncthreads();
    }

    const float b0 = bp[lr];
    const float b1 = (lr < 4) ? bp[16 + lr] : 0.0f;
    #pragma unroll
    for (int m = 0; m < 2; m++) {
        #pragma unroll
        for (int j = 0; j < 4; j++) {
            const float v0 = sacc[m][0][j] + b0;
            const float e0 = __expf(v0);
            const float v1 = sacc[m][1][j] + b1;
            const float e1 = (lr < 4) ? __expf(v1) : 0.0f;
            float Sp = e0 + e1;
            float Tp = e0 * v0 + ((lr < 4) ? e1 * v1 : 0.0f);
            #pragma unroll
            for (int o = 1; o < 16; o <<= 1) {
                Sp += __shfl_xor(Sp, o);
                Tp += __shfl_xor(Tp, o);
            }
            const float inv = 1.0f / Sp;
            const int row = m0 + w * 32 + m * 16 + lg * 4 + j;
            probs[(size_t)row * NAA + lr] = e0 * inv;
            if (lr < 4) probs[(size_t)row * NAA + 16 + lr] = e1 * inv;
            if (lr == 0) pe[row] = logf(Sp) - Tp * inv;
        }
    }
}

// ---------------------------------------------------------------------------
// bf16 MFMA GEMM, 256x256, BK=64, 8-phase pipeline + fragment caching
// (unchanged from r18/r19 best).
// ---------------------------------------------------------------------------
template<int OMODE, bool BIAS, bool RELU, int RESID>
__global__ __launch_bounds__(512, 2) void mgemm7(
    const unsigned short* __restrict__ A, int lda,
    const unsigned short* __restrict__ Bt, int ldb,
    void* __restrict__ Cv, int ldc,
    const float* __restrict__ bias,
    const void* __restrict__ R, int ldr,
    int K)
{
    __shared__ __align__(16) char lds[131072];

    const int t = threadIdx.x;
    const int w = t >> 6, l = t & 63;
    const int wr = w >> 2, wc = w & 3;
    const int lg = l >> 4, lr = l & 15;

    const int gx   = gridDim.x;
    const int nwg  = gx * gridDim.y;
    const int flat = blockIdx.x + gx * blockIdx.y;
    const int cpx  = nwg >> 3;
    const int logical = (flat & 7) * cpx + (flat >> 3);
    const int m0 = (logical / gx) * 256, n0 = (logical % gx) * 256;

    f32x4 acc[8][4];
    #pragma unroll
    for (int m = 0; m < 8; m++)
        #pragma unroll
        for (int n = 0; n < 4; n++)
            acc[m][n] = (f32x4){0.f, 0.f, 0.f, 0.f};

    const int srow = t >> 3;
    const int sch  = (t & 7) ^ (srow & 7);

    auto stageA = [&](int kt, int d, int h) {
        const char* src = (const char*)A +
            ((size_t)(m0 + h * 128 + srow) * lda + sch * 8) * 2 + (size_t)kt * 128;
        char* dst = lds + d * 65536 + h * 16384 + t * 16;
        load16_lds(src, dst);
        load16_lds(src + (size_t)64 * lda * 2, dst + 8192);
    };
    auto stageB = [&](int kt, int d, int h) {
        const char* src = (const char*)Bt +
            ((size_t)(n0 + h * 128 + srow) * ldb + sch * 8) * 2 + (size_t)kt * 128;
        char* dst = lds + d * 65536 + 32768 + h * 16384 + t * 16;
        load16_lds(src, dst);
        load16_lds(src + (size_t)64 * ldb * 2, dst + 8192);
    };

    int aoff[4], boff[2], sw[2];
    #pragma unroll
    for (int mi = 0; mi < 4; mi++) aoff[mi] = (mi * 32 + wr * 16 + lr) * 128;
    #pragma unroll
    for (int ni = 0; ni < 2; ni++) boff[ni] = (ni * 64 + wc * 16 + lr) * 128;
    #pragma unroll
    for (int ks = 0; ks < 2; ks++) sw[ks] = ((ks * 4 + lg) ^ (lr & 7)) << 4;

    short8 afc[2][4];
    short8 bfc0[2][2];
    short8 bfc1[2][2];

    const int NI = K >> 7;

#define MPHASE(D, MH, NH, LOADA, LOADB, BAR, STAGE_STMT, WAIT_STMT) do {       \
    const char* Abase_ = lds + (D) * 65536 + (MH) * 16384;                     \
    const char* Bbase_ = lds + (D) * 65536 + 32768 + (NH) * 16384;             \
    if (LOADA) {                                                               \
        _Pragma("unroll")                                                      \
        for (int ks_ = 0; ks_ < 2; ks_++)                                      \
            _Pragma("unroll")                                                  \
            for (int mi_ = 0; mi_ < 4; mi_++)                                  \
                afc[ks_][mi_] = *(const short8*)(Abase_ + aoff[mi_] + sw[ks_]);\
    }                                                                          \
    short8 (&bf_)[2][2] = (NH) ? bfc1 : bfc0;                                  \
    if (LOADB) {                                                               \
        _Pragma("unroll")                                                      \
        for (int ks_ = 0; ks_ < 2; ks_++)                                      \
            _Pragma("unroll")                                                  \
            for (int ni_ = 0; ni_ < 2; ni_++)                                  \
                bf_[ks_][ni_] = *(const short8*)(Bbase_ + boff[ni_] + sw[ks_]);\
    }                                                                          \
    STAGE_STMT;                                                                \
    WAIT_STMT;                                                                 \
    if (BAR) {                                                                 \
        __builtin_amdgcn_s_barrier();                                          \
        asm volatile("s_waitcnt lgkmcnt(0)" ::: "memory");                     \
        __builtin_amdgcn_sched_barrier(0);                                     \
    }                                                                          \
    __builtin_amdgcn_s_setprio(1);                                             \
    _Pragma("unroll")                                                          \
    for (int ks_ = 0; ks_ < 2; ks_++)                                          \
        _Pragma("unroll")                                                      \
        for (int mi_ = 0; mi_ < 4; mi_++)                                      \
            _Pragma("unroll")                                                  \
            for (int ni_ = 0; ni_ < 2; ni_++)                                  \
                acc[(MH) * 4 + mi_][(NH) * 2 + ni_] =                          \
                    __builtin_amdgcn_mfma_f32_16x16x32_bf16(                   \
                        afc[ks_][mi_], bf_[ks_][ni_],                          \
                        acc[(MH) * 4 + mi_][(NH) * 2 + ni_], 0, 0, 0);         \
    __builtin_amdgcn_s_setprio(0);                                             \
    asm volatile("" ::: "memory");                                             \
} while (0)

    stageA(0, 0, 0); stageB(0, 0, 0); stageB(0, 0, 1); stageA(0, 0, 1);
    stageA(1, 1, 0); stageB(1, 1, 0);
    asm volatile("s_waitcnt vmcnt(4)" ::: "memory");
    __builtin_amdgcn_s_barrier();
    asm volatile("" ::: "memory");

    for (int it = 0; it < NI; ++it) {
        const bool more = (it + 1 < NI);
        const int T1 = 2 * it + 1, T2 = 2 * it + 2, T3 = 2 * it + 3;

        MPHASE(0, 0, 0, 1, 1, 1, { stageB(T1, 1, 1); }, {});
        MPHASE(0, 0, 1, 0, 1, 1, { stageA(T1, 1, 1); }, {});
        MPHASE(0, 1, 0, 1, 0, 1, { if (more) stageA(T2, 0, 0); }, {});
        MPHASE(0, 1, 1, 0, 0, 0, { if (more) stageB(T2, 0, 0); },
               { if (more) { asm volatile("s_waitcnt vmcnt(4)" ::: "memory"); }
                 else      { asm volatile("s_waitcnt vmcnt(0)" ::: "memory"); } });
        MPHASE(1, 0, 0, 1, 1, 1, { if (more) stageA(T2, 0, 1); }, {});
        MPHASE(1, 0, 1, 0, 1, 1, { if (more) stageB(T2, 0, 1); }, {});
        MPHASE(1, 1, 0, 1, 0, 1, { if (more) stageA(T3, 1, 0); }, {});
        MPHASE(1, 1, 1, 0, 0, 0, { if (more) stageB(T3, 1, 0); },
               { if (more) { asm volatile("s_waitcnt vmcnt(4)" ::: "memory"); } });
    }
#undef MPHASE

    __syncthreads();   // all MFMA LDS reads done before epilogue reuses lds

    if (OMODE == 1) {
        unsigned short* cs = (unsigned short*)lds;
        #pragma unroll
        for (int nf = 0; nf < 4; nf++) {
            const int lcol = (nf >> 1) * 128 + (nf & 1) * 64 + wc * 16 + lr;
            const int col = n0 + lcol;
            const float bv = BIAS ? bias[col] : 0.0f;
            #pragma unroll
            for (int mf = 0; mf < 8; mf++) {
                const int lrow0 = (mf >> 2) * 128 + (mf & 3) * 32 + wr * 16 + lg * 4;
                #pragma unroll
                for (int j = 0; j < 4; j++) {
                    float v = acc[mf][nf][j] + bv;
                    if (RELU) v = fmaxf(v, 0.f);
                    const size_t grow = (size_t)(m0 + lrow0 + j);
                    if (RESID == 1) v += ((const float*)R)[grow * ldr + col];
                    if (RESID == 2) v += bf2f(((const unsigned short*)R)[grow * ldr + col]);
                    cs[(lrow0 + j) * 256 + lcol] = f2bf(v);
                }
            }
        }
        __syncthreads();
        unsigned short* Cp = (unsigned short*)Cv;
        #pragma unroll
        for (int i = 0; i < 16; i++) {
            const int slot = i * 512 + t;
            const int row = slot >> 5, c16 = slot & 31;
            short8 v = *(const short8*)(cs + row * 256 + c16 * 8);
            *(short8*)(Cp + (size_t)(m0 + row) * ldc + n0 + c16 * 8) = v;
        }
    } else {
        float* cf = (float*)lds;
        #pragma unroll
        for (int h = 0; h < 2; h++) {
            if (h) __syncthreads();
            #pragma unroll
            for (int nf = 0; nf < 4; nf++) {
                const int lcol = (nf >> 1) * 128 + (nf & 1) * 64 + wc * 16 + lr;
                const int col = n0 + lcol;
                const float bv = BIAS ? bias[col] : 0.0f;
                #pragma unroll
                for (int mi = 0; mi < 4; mi++) {
                    const int mf = h * 4 + mi;
                    const int lrow0 = (mf & 3) * 32 + wr * 16 + lg * 4;
                    #pragma unroll
                    for (int j = 0; j < 4; j++) {
                        float v = acc[mf][nf][j] + bv;
                        if (RELU) v = fmaxf(v, 0.f);
                        const size_t grow = (size_t)(m0 + h * 128 + lrow0 + j);
                        if (RESID == 1) v += ((const float*)R)[grow * ldr + col];
                        if (RESID == 2) v += bf2f(((const unsigned short*)R)[grow * ldr + col]);
                        cf[(lrow0 + j) * 256 + lcol] = v;
                    }
                }
            }
            __syncthreads();
            float* Cp = (float*)Cv;
            #pragma unroll
            for (int i = 0; i < 16; i++) {
                const int slot = i * 512 + t;
                const int row = slot >> 6, c4 = slot & 63;
                float4 v = *(const float4*)(cf + row * 256 + c4 * 4);
                *(float4*)(Cp + (size_t)(m0 + h * 128 + row) * ldc + n0 + c4 * 4) = v;
            }
        }
    }
}

// ---------------------------------------------------------------------------
// MFMA attention, pipelined staging. tb computed in-block from pe/ew/pos.
// ---------------------------------------------------------------------------
__global__ __launch_bounds__(256, 2) void attn_mfma(
    const unsigned short* __restrict__ QKV,
    const float* __restrict__ pe,
    const float* __restrict__ ew,
    const float* __restrict__ pos,
    unsigned short* __restrict__ AOb,
    float* __restrict__ lgout)
{
    const int flat = blockIdx.x + 4 * (blockIdx.y + 4 * blockIdx.z);
    const int logical = ((flat & 7) << 7) + (flat >> 3);
    const int qt = logical & 3;
    const int h  = (logical >> 2) & 3;
    const int b  = logical >> 4;
    const int t  = threadIdx.x;
    const int w  = t >> 6, l = t & 63;
    const int lr = l & 15, lg = l >> 4;
    const int qbase = qt * 128 + w * 32;

    const unsigned short* Qp = QKV;
    const unsigned short* Kp = QKV + 512;
    const unsigned short* Vp = QKV + 1024;

    __shared__ __align__(16) unsigned short Ks[2][8192];
    __shared__ __align__(16) unsigned short Vt[8192];
    __shared__ __align__(16) unsigned short Pl[8192];
    __shared__ float tbs[512];

    {
        const float e0 = ew[0];
        tbs[t]       = -pe[t]       * e0 + pos[t];
        tbs[t + 256] = -pe[t + 256] * e0 + pos[t + 256];
    }

    short8 qf[2][4];
    #pragma unroll
    for (int fc = 0; fc < 2; fc++) {
        const size_t qrow = (size_t)(b * LSEQ + qbase + fc * 16 + lr) * LDQKV + h * HDIM;
        #pragma unroll
        for (int ks = 0; ks < 4; ks++)
            qf[fc][ks] = *(const short8*)(Qp + qrow + ks * 32 + lg * 8);
    }

    f32x4 oacc[2][8];
    #pragma unroll
    for (int m = 0; m < 2; m++)
        #pragma unroll
        for (int n = 0; n < 8; n++)
            oacc[m][n] = (f32x4){0.f, 0.f, 0.f, 0.f};
    float lpart[2] = {0.f, 0.f};

    const float scale = 0.08838834764831845f;
    unsigned short* Plw = Pl + w * 2048;

    auto stageK = [&](int kt, int buf) {
        #pragma unroll
        for (int it = 0; it < 4; it++) {
            const int bi = it * 4 + w;
            const int r  = bi * 4 + lg;
            const int sc = lr ^ (r & 7);
            const char* src = (const char*)Kp +
                (size_t)(b * LSEQ + kt * 64 + r) * (LDQKV * 2) + h * 256 + sc * 16;
            load16_lds(src, (char*)Ks[buf] + bi * 1024);
        }
    };
    const int k0v = (l & 31) * 2;
    const int d0v = w * 32 + (l >> 5) * 16;

    stageK(0, 0);
    short8 vc0, vc1, vc2, vc3, vn0, vn1, vn2, vn3;
    {
        const size_t vrow = (size_t)(b * LSEQ + k0v) * LDQKV + h * HDIM + d0v;
        vc0 = *(const short8*)(Vp + vrow);
        vc1 = *(const short8*)(Vp + vrow + 8);
        vc2 = *(const short8*)(Vp + vrow + LDQKV);
        vc3 = *(const short8*)(Vp + vrow + LDQKV + 8);
    }

    #pragma unroll 2
    for (int kt = 0; kt < 8; ++kt) {
        asm volatile("" ::: "memory");
        __builtin_amdgcn_s_barrier();
        asm volatile("" ::: "memory");

        if (kt < 7) {
            stageK(kt + 1, (kt + 1) & 1);
            const size_t vrow = (size_t)(b * LSEQ + (kt + 1) * 64 + k0v) * LDQKV + h * HDIM + d0v;
            vn0 = *(const short8*)(Vp + vrow);
            vn1 = *(const short8*)(Vp + vrow + 8);
            vn2 = *(const short8*)(Vp + vrow + LDQKV);
            vn3 = *(const short8*)(Vp + vrow + LDQKV + 8);
        }
        asm volatile("" ::: "memory");

        #pragma unroll
        for (int j = 0; j < 16; j++) {
            const int d = d0v + j;
            unsigned short lo = (unsigned short)((j < 8) ? vc0[j] : vc1[j - 8]);
            unsigned short hi = (unsigned short)((j < 8) ? vc2[j] : vc3[j - 8]);
            unsigned int pk = (unsigned)lo | ((unsigned)hi << 16);
            const int addr = d * 128 + ((((k0v >> 3) ^ (d & 7))) << 4) + (k0v & 7) * 2;
            *(unsigned int*)((char*)Vt + addr) = pk;
        }

        if (kt < 7) { asm volatile("s_waitcnt vmcnt(8)" ::: "memory"); }
        else        { asm volatile("s_waitcnt vmcnt(0)" ::: "memory"); }
        asm volatile("s_waitcnt lgkmcnt(0)" ::: "memory");
        __builtin_amdgcn_s_barrier();
        __builtin_amdgcn_sched_barrier(0);

        const unsigned short* Ksb = Ks[kt & 1];

        f32x4 sacc[4][2];
        #pragma unroll
        for (int fm = 0; fm < 4; fm++)
            #pragma unroll
            for (int fc = 0; fc < 2; fc++)
                sacc[fm][fc] = (f32x4){0.f, 0.f, 0.f, 0.f};
        #pragma unroll
        for (int ks = 0; ks < 4; ks++) {
            short8 af[4];
            #pragma unroll
            for (int fm = 0; fm < 4; fm++) {
                const int r2 = fm * 16 + lr;
                af[fm] = *(const short8*)((const char*)Ksb +
                          r2 * 256 + (((ks * 4 + lg) ^ (lr & 7)) << 4));
            }
            #pragma unroll
            for (int fm = 0; fm < 4; fm++)
                #pragma unroll
                for (int fc = 0; fc < 2; fc++)
                    sacc[fm][fc] = __builtin_amdgcn_mfma_f32_16x16x32_bf16(
                        af[fm], qf[fc][ks], sacc[fm][fc], 0, 0, 0);
        }

        #pragma unroll
        for (int fm = 0; fm < 4; fm++) {
            #pragma unroll
            for (int fc = 0; fc < 2; fc++) {
                float p0 = sacc[fm][fc][0] * scale;
                float p1 = sacc[fm][fc][1] * scale;
                float p2 = sacc[fm][fc][2] * scale;
                float p3 = sacc[fm][fc][3] * scale;
                if (qt == 0 && w == 0 && fc == 0 && lr == 0) {
                    const int kb = kt * 64 + fm * 16 + lg * 4;
                    p0 += tbs[kb + 0]; p1 += tbs[kb + 1];
                    p2 += tbs[kb + 2]; p3 += tbs[kb + 3];
                }
                p0 = __expf(p0); p1 = __expf(p1);
                p2 = __expf(p2); p3 = __expf(p3);
                lpart[fc] += (p0 + p1) + (p2 + p3);
                const int rq = fc * 16 + lr;
                const int chunk = fm * 2 + (lg >> 1);
                const int addr = rq * 128 + ((chunk ^ (rq & 7)) << 4) + (lg & 1) * 8;
                unsigned int lo = (unsigned)f2bf(p0) | ((unsigned)f2bf(p1) << 16);
                unsigned int hi = (unsigned)f2bf(p2) | ((unsigned)f2bf(p3) << 16);
                *(uint2*)((char*)Plw + addr) = make_uint2(lo, hi);
            }
        }

        #pragma unroll
        for (int ks2 = 0; ks2 < 2; ks2++) {
            short8 pf[2];
            #pragma unroll
            for (int fm2 = 0; fm2 < 2; fm2++) {
                const int rq2 = fm2 * 16 + lr;
                pf[fm2] = *(const short8*)((const char*)Plw +
                           rq2 * 128 + (((ks2 * 4 + lg) ^ (rq2 & 7)) << 4));
            }
            #pragma unroll
            for (int fn = 0; fn < 8; fn++) {
                const int d = fn * 16 + lr;
                short8 vf = *(const short8*)((const char*)Vt +
                             d * 128 + (((ks2 * 4 + lg) ^ (d & 7)) << 4));
                #pragma unroll
                for (int fm2 = 0; fm2 < 2; fm2++)
                    oacc[fm2][fn] = __builtin_amdgcn_mfma_f32_16x16x32_bf16(
                        pf[fm2], vf, oacc[fm2][fn], 0, 0, 0);
            }
        }

        vc0 = vn0; vc1 = vn1; vc2 = vn2; vc3 = vn3;
    }

    float l0 = lpart[0], l1 = lpart[1];
    l0 += __shfl_xor(l0, 16); l0 += __shfl_xor(l0, 32);
    l1 += __shfl_xor(l1, 16); l1 += __shfl_xor(l1, 32);
    float* lw = (float*)Plw;
    if (lg == 0) { lw[lr] = l0; lw[16 + lr] = l1; }
    if (h == 0 && lg == 0) {
        lgout[b * LSEQ + qbase + lr]      = l0;
        lgout[b * LSEQ + qbase + 16 + lr] = l1;
    }
    __builtin_amdgcn_s_waitcnt(0);

    #pragma unroll
    for (int fm2 = 0; fm2 < 2; fm2++) {
        float linv[4];
        #pragma unroll
        for (int j = 0; j < 4; j++)
            linv[j] = 1.0f / lw[fm2 * 16 + lg * 4 + j];
        #pragma unroll
        for (int fn = 0; fn < 8; fn++) {
            const int d = fn * 16 + lr;
            #pragma unroll
            for (int j = 0; j < 4; j++) {
                const int q = qbase + fm2 * 16 + lg * 4 + j;
                AOb[(size_t)(b * LSEQ + q) * SDIM + h * HDIM + d] =
                    f2bf(oacc[fm2][fn][j] * linv[j]);
            }
        }
    }
}

// ---------------------------------------------------------------------------
// sw0: recompute h=0 scores, NORMALIZED W0 fp32. tb computed in-block.
// ---------------------------------------------------------------------------
__global__ __launch_bounds__(256, 2) void sw0_kernel(
    const unsigned short* __restrict__ QKV,
    const float* __restrict__ pe,
    const float* __restrict__ ew,
    const float* __restrict__ pos,
    const float* __restrict__ lsum,
    float* __restrict__ W0)
{
    const int flat = blockIdx.x + 4 * blockIdx.y;
    const int logical = ((flat & 7) << 5) + (flat >> 3);
    const int qt = logical & 3;
    const int b  = logical >> 2;
    const int t  = threadIdx.x;
    const int w  = t >> 6, l = t & 63;
    const int lr = l & 15, lg = l >> 4;
    const int qbase = qt * 128 + w * 32;

    const unsigned short* Qp = QKV;
    const unsigned short* Kp = QKV + 512;

    __shared__ __align__(16) unsigned short Ks[2][8192];
    __shared__ __align__(16) float Sc[4][32][68];
    __shared__ float tbs[512];

    {
        const float e0 = ew[0];
        tbs[t]       = -pe[t]       * e0 + pos[t];
        tbs[t + 256] = -pe[t + 256] * e0 + pos[t + 256];
    }

    short8 qf[2][4];
    #pragma unroll
    for (int fc = 0; fc < 2; fc++) {
        const size_t qrow = (size_t)(b * LSEQ + qbase + fc * 16 + lr) * LDQKV;
        #pragma unroll
        for (int ks = 0; ks < 4; ks++)
            qf[fc][ks] = *(const short8*)(Qp + qrow + ks * 32 + lg * 8);
    }

    float linv[2];
    linv[0] = 1.0f / lsum[b * LSEQ + qbase + lr];
    linv[1] = 1.0f / lsum[b * LSEQ + qbase + 16 + lr];

    const float scale = 0.08838834764831845f;

    auto stageK = [&](int kt, int buf) {
        #pragma unroll
        for (int it = 0; it < 4; it++) {
            const int bi = it * 4 + w;
            const int r  = bi * 4 + lg;
            const int sc = lr ^ (r & 7);
            const char* src = (const char*)Kp +
                (size_t)(b * LSEQ + kt * 64 + r) * (LDQKV * 2) + sc * 16;
            load16_lds(src, (char*)Ks[buf] + bi * 1024);
        }
    };

    stageK(0, 0);

    for (int kt = 0; kt < 8; ++kt) {
        asm volatile("" ::: "memory");
        __builtin_amdgcn_s_barrier();
        asm volatile("" ::: "memory");

        if (kt < 7) stageK(kt + 1, (kt + 1) & 1);

        if (kt < 7) { asm volatile("s_waitcnt vmcnt(4)" ::: "memory"); }
        else        { asm volatile("s_waitcnt vmcnt(0)" ::: "memory"); }
        __builtin_amdgcn_s_barrier();
        __builtin_amdgcn_sched_barrier(0);

        const unsigned short* Ksb = Ks[kt & 1];

        f32x4 sacc[4][2];
        #pragma unroll
        for (int fm = 0; fm < 4; fm++)
            #pragma unroll
            for (int fc = 0; fc < 2; fc++)
                sacc[fm][fc] = (f32x4){0.f, 0.f, 0.f, 0.f};
        #pragma unroll
        for (int ks = 0; ks < 4; ks++) {
            short8 af[4];
            #pragma unroll
            for (int fm = 0; fm < 4; fm++) {
                const int r2 = fm * 16 + lr;
                af[fm] = *(const short8*)((const char*)Ksb +
                          r2 * 256 + (((ks * 4 + lg) ^ (lr & 7)) << 4));
            }
            #pragma unroll
            for (int fm = 0; fm < 4; fm++)
                #pragma unroll
                for (int fc = 0; fc < 2; fc++)
                    sacc[fm][fc] = __builtin_amdgcn_mfma_f32_16x16x32_bf16(
                        af[fm], qf[fc][ks], sacc[fm][fc], 0, 0, 0);
        }

        #pragma unroll
        for (int fm = 0; fm < 4; fm++) {
            #pragma unroll
            for (int fc = 0; fc < 2; fc++) {
                float p0 = sacc[fm][fc][0] * scale;
                float p1 = sacc[fm][fc][1] * scale;
                float p2 = sacc[fm][fc][2] * scale;
                float p3 = sacc[fm][fc][3] * scale;
                if (qt == 0 && w == 0 && fc == 0 && lr == 0) {
                    const int kb = kt * 64 + fm * 16 + lg * 4;
                    p0 += tbs[kb + 0]; p1 += tbs[kb + 1];
                    p2 += tbs[kb + 2]; p3 += tbs[kb + 3];
                }
                p0 = __expf(p0) * linv[fc]; p1 = __expf(p1) * linv[fc];
                p2 = __expf(p2) * linv[fc]; p3 = __expf(p3) * linv[fc];
                *(float4*)&Sc[w][fc * 16 + lr][fm * 16 + lg * 4] =
                    make_float4(p0, p1, p2, p3);
            }
        }

        #pragma unroll
        for (int i = 0; i < 8; i++) {
            const int row = i * 4 + lg;
            float4 v = *(const float4*)&Sc[w][row][lr * 4];
            *(float4*)(W0 + (size_t)(b * LSEQ + qbase + row) * LSEQ +
                       kt * 64 + lr * 4) = v;
        }
    }
}

// ---------------------------------------------------------------------------
extern "C" void kernel_launch(void* const* d_in, const int* in_sizes, int n_in,
                              void* d_out, int out_size, void* d_ws, size_t ws_size,
                              hipStream_t stream)
{
    const float* s   = (const float*)d_in[0];
    const float* z   = (const float*)d_in[1];
    const float* wq  = (const float*)d_in[2];
    const float* bq  = (const float*)d_in[3];
    const float* wk  = (const float*)d_in[4];
    const float* bk  = (const float*)d_in[5];
    const float* wv  = (const float*)d_in[6];
    const float* bv  = (const float*)d_in[7];
    const float* wo  = (const float*)d_in[8];
    const float* bo  = (const float*)d_in[9];
    const float* wp  = (const float*)d_in[10];
    const float* bp  = (const float*)d_in[11];
    const float* pos = (const float*)d_in[12];
    const float* ew  = (const float*)d_in[13];
    const float* lng = (const float*)d_in[14];
    const float* lnb = (const float*)d_in[15];
    const float* w1  = (const float*)d_in[16];
    const float* b1  = (const float*)d_in[17];
    const float* w2  = (const float*)d_in[18];
    const float* b2  = (const float*)d_in[19];

    float* out = (float*)d_out;
    const size_t oz  = (size_t)NROWS * SDIM;
    const size_t ow  = oz + (size_t)NROWS * 64;
    const size_t ope = ow + (size_t)NROWS * LSEQ;
    const size_t opr = ope + (size_t)NROWS;

    // workspace layout (bytes)
    char* wsb = (char*)d_ws;
    unsigned short* QKV = (unsigned short*)(wsb);
    unsigned short* F   = (unsigned short*)(wsb);
    unsigned short* Xb  = (unsigned short*)(wsb + 100663296);
    unsigned short* s2b = (unsigned short*)(wsb + 134217728);
    unsigned short* hb  = (unsigned short*)(wsb + 167772160);
    unsigned short* wqkvt = (unsigned short*)(wsb + 234881024);
    unsigned short* wot = wqkvt + 786432;
    unsigned short* w1t = wqkvt + 1048576;    // [2048][512]
    unsigned short* w2t = wqkvt + 2097152;    // [512][2048]
    unsigned short* wpT = wqkvt + 3145728;    // [32][512]
    float* bqkv = (float*)(wsb + 234881024 + 6324224);
    float* lgv  = bqkv + 2048;

    // 0. fused prep: weight transposes + wpT + bias pack + z + LN1
    prep_kernel<<<13377, 256, 0, stream>>>(
        wq, wk, wv, wo, w1, w2, wp, bq, bk, bv, z, s,
        wqkvt, wot, w1t, w2t, wpT, bqkv, out + oz, Xb);

    // 1. profile softmax + entropy (MFMA)
    profile_kernel<<<256, 256, 0, stream>>>(Xb, wpT, bp, out + opr, out + ope);

    // 2. fused QKV projection -> QKV bf16 [32768][1536]
    mgemm7<1, true, false, 0><<<dim3(6, 128), 512, 0, stream>>>(
        Xb, 512, wqkvt, 512, QKV, LDQKV, bqkv, nullptr, 0, 512);

    // 3. MFMA attention (tb computed in-block) -> attn_out bf16 (Xb) + rowsums
    attn_mfma<<<dim3(4, NHEAD, BATCH), 256, 0, stream>>>(
        QKV, out + ope, ew, pos, Xb, lgv);

    // 3b. head-0 normalized attention weights (fp32)
    sw0_kernel<<<dim3(4, BATCH), 256, 0, stream>>>(
        QKV, out + ope, ew, pos, lgv, out + ow);

    // 4. s2 = s + attn_out @ wo + bo  -> bf16 s2b
    mgemm7<1, true, false, 1><<<dim3(2, 128), 512, 0, stream>>>(
        Xb, 512, wot, 512, s2b, 512, bo, s, 512, 512);

    // 5. h = LN(s2)*g + b -> bf16 (bf16 input)
    ln_kernel<1, true><<<NROWS / 4, 256, 0, stream>>>(s2b, hb, lng, lnb);

    // 6. FFN1: F = relu(h @ w1 + b1), bf16 [32768][2048]
    mgemm7<1, true, true, 0><<<dim3(8, 128), 512, 0, stream>>>(
        hb, 512, w1t, 512, F, 2048, b1, nullptr, 0, 512);

    // 7. FFN2: out0 = F @ w2 + b2 + s2b
    mgemm7<0, true, false, 2><<<dim3(2, 128), 512, 0, stream>>>(
        F, 2048, w2t, 2048, out, 512, b2, s2b, 512, 2048);
}